// Round 2
// baseline (3782.158 us; speedup 1.0000x reference)
//
#include <hip/hip_runtime.h>

__device__ __forceinline__ float leaky01(float v) { return v > 0.f ? v : 0.01f * v; }

// ---------------- CSR build ----------------
__global__ void init_k(int* cnt, float* deg, int N) {
    int i = blockIdx.x * 256 + threadIdx.x;
    if (i < N) { cnt[i] = 1; deg[i] = 1.0f; }  // self-loop: count 1, weight 1
}

__global__ void count_k(const int* __restrict__ ei, const float* __restrict__ ew,
                        int* cnt, float* deg, int E) {
    int e = blockIdx.x * 256 + threadIdx.x;
    if (e < E) {
        int dst = ei[E + e];
        atomicAdd(&cnt[dst], 1);
        atomicAdd(&deg[dst], ew[e]);
    }
}

__launch_bounds__(1024)
__global__ void scan_k(const int* __restrict__ cnt, int* rp, int n) {
    __shared__ int wsum[16];
    int tid = threadIdx.x; int lane = tid & 63, wid = tid >> 6;
    int base = 0;
    for (int start = 0; start < n; start += 4096) {
        int v[4]; int s = 0;
        #pragma unroll
        for (int j = 0; j < 4; ++j) {
            int i = start + tid * 4 + j;
            v[j] = (i < n) ? cnt[i] : 0; s += v[j];
        }
        int sc = s;
        #pragma unroll
        for (int off = 1; off < 64; off <<= 1) {
            int t = __shfl_up(sc, off);
            if (lane >= off) sc += t;
        }
        if (lane == 63) wsum[wid] = sc;
        __syncthreads();
        if (wid == 0) {
            int ws = (lane < 16) ? wsum[lane] : 0;
            #pragma unroll
            for (int off = 1; off < 16; off <<= 1) {
                int t = __shfl_up(ws, off);
                if (lane >= off) ws += t;
            }
            if (lane < 16) wsum[lane] = ws;
        }
        __syncthreads();
        int wbase = (wid > 0) ? wsum[wid - 1] : 0;
        int excl = base + wbase + (sc - s);
        #pragma unroll
        for (int j = 0; j < 4; ++j) {
            int i = start + tid * 4 + j;
            if (i < n) rp[i] = excl;
            excl += v[j];
        }
        int total = wsum[15];
        __syncthreads();
        base += total;
    }
    if (tid == 0) rp[n] = base;
}

__global__ void post_k(const int* __restrict__ rp, int* fill, int* csrc, float* cw,
                       float* deg_dinv, int N) {
    int i = blockIdx.x * 256 + threadIdx.x;
    if (i < N) {
        int p = rp[i];
        fill[i] = p + 1;          // slot p reserved for self-loop
        csrc[p] = i;
        cw[p] = 1.0f;
        deg_dinv[i] = rsqrtf(deg_dinv[i]);  // deg >= 1 always
    }
}

__global__ void scat_k(const int* __restrict__ ei, const float* __restrict__ ew,
                       int* fill, int* csrc, float* cw, int E) {
    int e = blockIdx.x * 256 + threadIdx.x;
    if (e < E) {
        int dst = ei[E + e];
        int pos = atomicAdd(&fill[dst], 1);
        csrc[pos] = ei[e];
        cw[pos] = ew[e];
    }
}

__global__ void coef_k(const int* __restrict__ rp, const int* __restrict__ csrc,
                       float* cw, const float* __restrict__ dinv, int N) {
    int i = blockIdx.x * 256 + threadIdx.x;
    if (i < N) {
        float di = dinv[i];
        int end = rp[i + 1];
        for (int s = rp[i]; s < end; ++s)
            cw[s] = dinv[csrc[s]] * cw[s] * di;
    }
}

// ---------------- GEMM: out[N,128] = A[N,K] @ W[K,128] (all fp32) ----------------
// MODE 0: A = x (fp32, K=128).  MODE 1: A = gathered [poi|cat|feat3], K=403.
template <int MODE>
__launch_bounds__(256)
__global__ void gemm_k(const float* __restrict__ x,
                       const int* __restrict__ poi_ids, const int* __restrict__ cat_ids,
                       const float* __restrict__ feat3,
                       const float* __restrict__ poi_emb, const float* __restrict__ cat_emb,
                       const float* __restrict__ W,
                       float* __restrict__ out, int N, int K) {
    __shared__ __align__(16) float AsT[32][68];   // [kk][row], stride 68 (16B-aligned rows)
    __shared__ __align__(16) float Ws[32][128];
    int tid = threadIdx.x;
    int tx = tid & 31, ty = tid >> 5;   // tx -> 4 cols, ty -> 8 rows
    int i0 = blockIdx.x * 64;
    float4 acc[8];
    #pragma unroll
    for (int r = 0; r < 8; ++r) acc[r] = make_float4(0.f, 0.f, 0.f, 0.f);

    int nchunk = (K + 31) >> 5;
    for (int ch = 0; ch < nchunk; ++ch) {
        int k0 = ch << 5;
        #pragma unroll
        for (int it = 0; it < 8; ++it) {
            int idx = tid + it * 256;         // 0..2047
            int kk = idx & 31, r = idx >> 5;
            int i = i0 + r, k = k0 + kk;
            float v = 0.f;
            if (i < N && k < K) {
                if (MODE == 0) v = x[(size_t)i * 128 + k];
                else {
                    if (k < 300)      v = poi_emb[(size_t)poi_ids[i] * 300 + k];
                    else if (k < 400) v = cat_emb[(size_t)cat_ids[i] * 100 + (k - 300)];
                    else              v = feat3[(size_t)i * 3 + (k - 400)];
                }
            }
            AsT[kk][r] = v;
        }
        #pragma unroll
        for (int it = 0; it < 4; ++it) {
            int idx = tid + it * 256;         // 0..1023 float4s
            int c4 = idx & 31, kk = idx >> 5;
            int k = k0 + kk;
            float4 wv = make_float4(0.f, 0.f, 0.f, 0.f);
            if (k < K) wv = *(const float4*)&W[(size_t)k * 128 + c4 * 4];
            *(float4*)&Ws[kk][c4 * 4] = wv;
        }
        __syncthreads();
        #pragma unroll
        for (int kk = 0; kk < 32; ++kk) {
            float4 w = *(const float4*)&Ws[kk][tx * 4];
            const float* ap = &AsT[kk][ty * 8];
            float4 a0 = *(const float4*)ap;
            float4 a1 = *(const float4*)(ap + 4);
            float av;
            av = a0.x; acc[0].x += av * w.x; acc[0].y += av * w.y; acc[0].z += av * w.z; acc[0].w += av * w.w;
            av = a0.y; acc[1].x += av * w.x; acc[1].y += av * w.y; acc[1].z += av * w.z; acc[1].w += av * w.w;
            av = a0.z; acc[2].x += av * w.x; acc[2].y += av * w.y; acc[2].z += av * w.z; acc[2].w += av * w.w;
            av = a0.w; acc[3].x += av * w.x; acc[3].y += av * w.y; acc[3].z += av * w.z; acc[3].w += av * w.w;
            av = a1.x; acc[4].x += av * w.x; acc[4].y += av * w.y; acc[4].z += av * w.z; acc[4].w += av * w.w;
            av = a1.y; acc[5].x += av * w.x; acc[5].y += av * w.y; acc[5].z += av * w.z; acc[5].w += av * w.w;
            av = a1.z; acc[6].x += av * w.x; acc[6].y += av * w.y; acc[6].z += av * w.z; acc[6].w += av * w.w;
            av = a1.w; acc[7].x += av * w.x; acc[7].y += av * w.y; acc[7].z += av * w.z; acc[7].w += av * w.w;
        }
        __syncthreads();
    }
    #pragma unroll
    for (int r = 0; r < 8; ++r) {
        int i = i0 + ty * 8 + r;
        if (i < N) *(float4*)&out[(size_t)i * 128 + tx * 4] = acc[r];
    }
}

// ---------------- aggregation: g[dst,:] = sum coef * xw[src,:] + bias ----------------
// wave per (node, 32-channel chunk); chunk-major block ordering for L2 locality
__global__ void agg_k(const float* __restrict__ xw, const int* __restrict__ rp,
                      const int* __restrict__ csrc, const float* __restrict__ cw,
                      const float* __restrict__ bias, float* __restrict__ g,
                      int N, int NB) {
    int tid = threadIdx.x;
    int wave = tid >> 6, lane = tid & 63;
    int bid = blockIdx.x;
    int chunk = bid / NB, nb = bid % NB;
    int node = nb * 4 + wave;
    if (node >= N) return;
    int c = chunk * 32 + (lane & 31);
    int s = rp[node] + (lane >> 5);
    int end = rp[node + 1];
    float acc = 0.f;
    for (; s < end; s += 2) {
        int src = csrc[s];
        float cf = cw[s];
        acc += cf * xw[(size_t)src * 128 + c];
    }
    acc += __shfl_xor(acc, 32);
    if (lane < 32) g[(size_t)node * 128 + c] = acc + bias[c];
}

// ---------------- GraphNorm moments ----------------
__global__ void moments_k(const float* __restrict__ g, float* mom, int n128) {
    __shared__ float s1s[256], s2s[256];
    int tid = threadIdx.x;
    long long T = (long long)gridDim.x * 256;
    float s1 = 0.f, s2 = 0.f;
    for (long long idx = (long long)blockIdx.x * 256 + tid; idx < n128; idx += T) {
        float v = g[idx]; s1 += v; s2 += v * v;
    }
    s1s[tid] = s1; s2s[tid] = s2;
    __syncthreads();
    if (tid < 128) {
        atomicAdd(&mom[tid], s1s[tid] + s1s[tid + 128]);
        atomicAdd(&mom[128 + tid], s2s[tid] + s2s[tid + 128]);
    }
}

// x += leaky( gamma*rsqrt(var+eps)*(g - alpha*mean) + beta )
__global__ void normresid_k(float* __restrict__ x, const float* __restrict__ g,
                            const float* __restrict__ mom,
                            const float* __restrict__ gamma, const float* __restrict__ beta,
                            const float* __restrict__ alpha, int n128, int N) {
    __shared__ float sc[128], sh[128];
    int tid = threadIdx.x;
    if (tid < 128) {
        float m = mom[tid] / (float)N;
        float a = alpha[tid];
        float var = mom[128 + tid] / (float)N - 2.f * a * m * m + a * a * m * m;
        float s = gamma[tid] * rsqrtf(var + 1e-5f);
        sc[tid] = s;
        sh[tid] = beta[tid] - s * a * m;
    }
    __syncthreads();
    for (long long idx = (long long)blockIdx.x * 256 + tid; idx < n128;
         idx += (long long)gridDim.x * 256) {
        int c = (int)(idx & 127);
        float v = sc[c] * g[idx] + sh[c];
        x[idx] += leaky01(v);
    }
}

__global__ void leaky_write_k(const float* __restrict__ g, float* __restrict__ x, int n128) {
    long long i = (long long)blockIdx.x * 256 + threadIdx.x;
    if (i < n128) x[i] = leaky01(g[i]);
}

// ---------------- GAT pieces ----------------
__global__ void alar_k(const float* __restrict__ xw, const float* __restrict__ asrc,
                       const float* __restrict__ adst, float* al, float* ar, int N) {
    __shared__ float ls[128], ld[128];
    int tid = threadIdx.x;
    if (tid < 128) { ls[tid] = asrc[tid]; ld[tid] = adst[tid]; }
    __syncthreads();
    int i = blockIdx.x * 256 + tid;
    if (i >= N) return;
    const float* row = xw + (size_t)i * 128;
    float a = 0.f, b = 0.f;
    #pragma unroll 4
    for (int c = 0; c < 128; c += 4) {
        float4 v = *(const float4*)(row + c);
        a += v.x * ls[c] + v.y * ls[c + 1] + v.z * ls[c + 2] + v.w * ls[c + 3];
        b += v.x * ld[c] + v.y * ld[c + 1] + v.z * ld[c + 2] + v.w * ld[c + 3];
    }
    al[i] = a; ar[i] = b;
}

__global__ void att_k(const float* __restrict__ al, const float* __restrict__ ar,
                      const int* __restrict__ rp, const int* __restrict__ csrc,
                      float* att, int N) {
    int tid = threadIdx.x;
    int wave = tid >> 6, lane = tid & 63;
    int node = blockIdx.x * 4 + wave;
    if (node >= N) return;
    int start = rp[node], end = rp[node + 1];
    float ari = ar[node];
    float m = -1e30f;
    for (int s = start + lane; s < end; s += 64) {
        float e = al[csrc[s]] + ari; e = e > 0.f ? e : 0.2f * e;
        m = fmaxf(m, e);
    }
    #pragma unroll
    for (int off = 32; off; off >>= 1) m = fmaxf(m, __shfl_xor(m, off));
    float dsum = 0.f;
    for (int s = start + lane; s < end; s += 64) {
        float e = al[csrc[s]] + ari; e = e > 0.f ? e : 0.2f * e;
        dsum += __expf(e - m);
    }
    #pragma unroll
    for (int off = 32; off; off >>= 1) dsum += __shfl_xor(dsum, off);
    float inv = 1.f / dsum;
    for (int s = start + lane; s < end; s += 64) {
        float e = al[csrc[s]] + ari; e = e > 0.f ? e : 0.2f * e;
        att[s] = __expf(e - m) * inv;
    }
}

// ---------------- output conv + FC head ----------------
__global__ void ydot_k(const float* __restrict__ x, const float* __restrict__ Wout,
                       float* yv, int N) {
    __shared__ float w[128];
    int tid = threadIdx.x;
    if (tid < 128) w[tid] = Wout[tid];
    __syncthreads();
    int i = blockIdx.x * 256 + tid;
    if (i >= N) return;
    const float* row = x + (size_t)i * 128;
    float acc = 0.f;
    #pragma unroll 4
    for (int c = 0; c < 128; c += 4) {
        float4 v = *(const float4*)(row + c);
        acc += v.x * w[c] + v.y * w[c + 1] + v.z * w[c + 2] + v.w * w[c + 3];
    }
    yv[i] = acc;
}

__global__ void aggs_k(const float* __restrict__ yv, const int* __restrict__ rp,
                       const int* __restrict__ csrc, const float* __restrict__ cw,
                       const float* __restrict__ b_out, float* xs, int N) {
    int i = blockIdx.x * 256 + threadIdx.x;
    if (i >= N) return;
    float acc = 0.f;
    int end = rp[i + 1];
    for (int s = rp[i]; s < end; ++s) acc += cw[s] * yv[csrc[s]];
    acc += b_out[0];
    xs[i] = leaky01(acc);
}

__global__ void fc1_k(const float* __restrict__ xs, const float* __restrict__ W1,
                      float* hacc, int N) {
    __shared__ float sd[256];
    int tid = threadIdx.x;
    int j = tid & 127, half = tid >> 7;
    int r0 = blockIdx.x * 256;
    float acc = 0.f;
    for (int rr = half; rr < 256; rr += 2) {
        int r = r0 + rr;
        if (r < N) acc += xs[r] * W1[(size_t)r * 128 + j];
    }
    sd[tid] = acc;
    __syncthreads();
    if (tid < 128) atomicAdd(&hacc[tid], sd[tid] + sd[tid + 128]);
}

__global__ void fc2_k(const float* __restrict__ hacc, const float* __restrict__ b1,
                      const float* __restrict__ W2, const float* __restrict__ b2v,
                      float* out, int P) {
    __shared__ float hs[128];
    int tid = threadIdx.x;
    if (tid < 128) {
        float h = hacc[tid] + b1[tid];
        hs[tid] = h > 0.f ? h : 0.f;
    }
    __syncthreads();
    int p = blockIdx.x * 256 + tid;
    if (p >= P) return;
    float acc = 0.f;
    #pragma unroll 8
    for (int j = 0; j < 128; ++j) acc += hs[j] * W2[(size_t)j * P + p];
    acc += b2v[p];
    out[p] = acc > 0.f ? acc : 0.f;
}

// ---------------- launcher ----------------
extern "C" void kernel_launch(void* const* d_in, const int* in_sizes, int n_in,
                              void* d_out, int out_size, void* d_ws, size_t ws_size,
                              hipStream_t stream) {
    const int*   poi_ids  = (const int*)d_in[0];
    const int*   cat_ids  = (const int*)d_in[1];
    const float* feat3    = (const float*)d_in[2];
    const int*   ei       = (const int*)d_in[3];
    const float* ew       = (const float*)d_in[4];
    const float* poi_emb  = (const float*)d_in[5];
    const float* cat_emb  = (const float*)d_in[6];
    const float* Win      = (const float*)d_in[7];
    const float* b_in     = (const float*)d_in[8];
    const float* gcn_W    = (const float*)d_in[9];
    const float* gcn_b    = (const float*)d_in[10];
    const float* gn_gamma = (const float*)d_in[11];
    const float* gn_beta  = (const float*)d_in[12];
    const float* gn_alpha = (const float*)d_in[13];
    const float* gat_W    = (const float*)d_in[14];
    const float* gat_asrc = (const float*)d_in[15];
    const float* gat_adst = (const float*)d_in[16];
    const float* gat_b    = (const float*)d_in[17];
    const float* Wout     = (const float*)d_in[18];
    const float* b_out    = (const float*)d_in[19];
    const float* fc_W1    = (const float*)d_in[20];
    const float* fc_b1    = (const float*)d_in[21];
    const float* fc_W2    = (const float*)d_in[22];
    const float* fc_b2    = (const float*)d_in[23];

    const int N = in_sizes[0];
    const int E = in_sizes[4];
    const int P = out_size;
    const int TOT = E + N;
    const int n128 = N * 128;

    // workspace carve (256B aligned)
    char* w = (char*)d_ws;
    size_t off = 0;
    auto take = [&](size_t bytes) -> char* {
        char* p = w + off;
        off = (off + bytes + 255) & ~(size_t)255;
        return p;
    };
    float* x    = (float*)take((size_t)n128 * 4);
    float* g    = (float*)take((size_t)n128 * 4);
    float* xw   = (float*)take((size_t)n128 * 4);
    int*   rp   = (int*)take((size_t)(N + 1) * 4);
    int*   cnt  = (int*)take((size_t)N * 4);
    int*   fill = (int*)take((size_t)N * 4);
    float* dinv = (float*)take((size_t)N * 4);
    int*   csrc = (int*)take((size_t)TOT * 4);
    float* cw   = (float*)take((size_t)TOT * 4);
    float* att  = (float*)take((size_t)TOT * 4);
    float* al   = (float*)take((size_t)N * 4);
    float* ar   = (float*)take((size_t)N * 4);
    float* yv   = (float*)take((size_t)N * 4);
    float* xs   = (float*)take((size_t)N * 4);
    float* mom  = (float*)take((size_t)(10 * 256 + 128) * 4);  // 10 graphnorm slots + hacc
    float* hacc = mom + 10 * 256;

    const int gN    = (N + 255) / 256;
    const int gE    = (E + 255) / 256;
    const int gGEMM = (N + 63) / 64;
    const int NB    = (N + 3) / 4;
    const int gAGG  = 4 * NB;
    const int gEW   = (n128 + 255) / 256;
    const int gP    = (P + 255) / 256;

    hipMemsetAsync(mom, 0, (size_t)(10 * 256 + 128) * 4, stream);

    // CSR build
    init_k<<<gN, 256, 0, stream>>>(cnt, dinv, N);              // dinv holds deg for now
    count_k<<<gE, 256, 0, stream>>>(ei, ew, cnt, dinv, E);
    scan_k<<<1, 1024, 0, stream>>>(cnt, rp, N);
    post_k<<<gN, 256, 0, stream>>>(rp, fill, csrc, cw, dinv, N);  // deg -> dinv in-place
    scat_k<<<gE, 256, 0, stream>>>(ei, ew, fill, csrc, cw, E);
    coef_k<<<gN, 256, 0, stream>>>(rp, csrc, cw, dinv, N);

    // input GCN conv: feat @ Win -> agg -> leaky -> x
    gemm_k<1><<<gGEMM, 256, 0, stream>>>(nullptr, poi_ids, cat_ids, feat3, poi_emb, cat_emb,
                                         Win, xw, N, 403);
    agg_k<<<gAGG, 256, 0, stream>>>(xw, rp, csrc, cw, b_in, g, N, NB);
    leaky_write_k<<<gEW, 256, 0, stream>>>(g, x, n128);

    // 5 GcnUnits: (GCNConv -> GraphNorm -> leaky -> +x), (GATConv -> GraphNorm -> leaky -> +x)
    for (int l = 0; l < 5; ++l) {
        // GCN half
        gemm_k<0><<<gGEMM, 256, 0, stream>>>(x, nullptr, nullptr, nullptr, nullptr, nullptr,
                                             gcn_W + (size_t)l * 128 * 128, xw, N, 128);
        agg_k<<<gAGG, 256, 0, stream>>>(xw, rp, csrc, cw, gcn_b + l * 128, g, N, NB);
        moments_k<<<240, 256, 0, stream>>>(g, mom + (2 * l) * 256, n128);
        normresid_k<<<1024, 256, 0, stream>>>(x, g, mom + (2 * l) * 256,
                                              gn_gamma + l * 128, gn_beta + l * 128,
                                              gn_alpha + l * 128, n128, N);
        // GAT half
        gemm_k<0><<<gGEMM, 256, 0, stream>>>(x, nullptr, nullptr, nullptr, nullptr, nullptr,
                                             gat_W + (size_t)l * 128 * 128, xw, N, 128);
        alar_k<<<gN, 256, 0, stream>>>(xw, gat_asrc + l * 128, gat_adst + l * 128, al, ar, N);
        att_k<<<NB, 256, 0, stream>>>(al, ar, rp, csrc, att, N);
        agg_k<<<gAGG, 256, 0, stream>>>(xw, rp, csrc, att, gat_b + l * 128, g, N, NB);
        moments_k<<<240, 256, 0, stream>>>(g, mom + (2 * l + 1) * 256, n128);
        normresid_k<<<1024, 256, 0, stream>>>(x, g, mom + (2 * l + 1) * 256,
                                              gn_gamma + l * 128, gn_beta + l * 128,
                                              gn_alpha + l * 128, n128, N);
    }

    // output conv (C -> 1) + leaky
    ydot_k<<<gN, 256, 0, stream>>>(x, Wout, yv, N);
    aggs_k<<<gN, 256, 0, stream>>>(yv, rp, csrc, cw, b_out, xs, N);

    // FC head
    fc1_k<<<(N + 255) / 256, 256, 0, stream>>>(xs, fc_W1, hacc, N);
    fc2_k<<<gP, 256, 0, stream>>>(hacc, fc_b1, fc_W2, fc_b2, (float*)d_out, P);
}

// Round 3
// 2302.362 us; speedup vs baseline: 1.6427x; 1.6427x over previous
//
#include <hip/hip_runtime.h>

__device__ __forceinline__ float leaky01(float v) { return v > 0.f ? v : 0.01f * v; }

// ---------------- CSR build ----------------
__global__ void init_k(int* cnt, float* deg, int N) {
    int i = blockIdx.x * 256 + threadIdx.x;
    if (i < N) { cnt[i] = 1; deg[i] = 1.0f; }  // self-loop: count 1, weight 1
}

__global__ void count_k(const int* __restrict__ ei, const float* __restrict__ ew,
                        int* cnt, float* deg, int E) {
    int e = blockIdx.x * 256 + threadIdx.x;
    if (e < E) {
        int dst = ei[E + e];
        atomicAdd(&cnt[dst], 1);
        atomicAdd(&deg[dst], ew[e]);
    }
}

__launch_bounds__(1024)
__global__ void scan_k(const int* __restrict__ cnt, int* rp, int n) {
    __shared__ int wsum[16];
    int tid = threadIdx.x; int lane = tid & 63, wid = tid >> 6;
    int base = 0;
    for (int start = 0; start < n; start += 4096) {
        int v[4]; int s = 0;
        #pragma unroll
        for (int j = 0; j < 4; ++j) {
            int i = start + tid * 4 + j;
            v[j] = (i < n) ? cnt[i] : 0; s += v[j];
        }
        int sc = s;
        #pragma unroll
        for (int off = 1; off < 64; off <<= 1) {
            int t = __shfl_up(sc, off);
            if (lane >= off) sc += t;
        }
        if (lane == 63) wsum[wid] = sc;
        __syncthreads();
        if (wid == 0) {
            int ws = (lane < 16) ? wsum[lane] : 0;
            #pragma unroll
            for (int off = 1; off < 16; off <<= 1) {
                int t = __shfl_up(ws, off);
                if (lane >= off) ws += t;
            }
            if (lane < 16) wsum[lane] = ws;
        }
        __syncthreads();
        int wbase = (wid > 0) ? wsum[wid - 1] : 0;
        int excl = base + wbase + (sc - s);
        #pragma unroll
        for (int j = 0; j < 4; ++j) {
            int i = start + tid * 4 + j;
            if (i < n) rp[i] = excl;
            excl += v[j];
        }
        int total = wsum[15];
        __syncthreads();
        base += total;
    }
    if (tid == 0) rp[n] = base;
}

__global__ void post_k(const int* __restrict__ rp, int* fill, int* csrc, float* cw,
                       float* deg_dinv, int N) {
    int i = blockIdx.x * 256 + threadIdx.x;
    if (i < N) {
        int p = rp[i];
        fill[i] = p + 1;          // slot p reserved for self-loop
        csrc[p] = i;
        cw[p] = 1.0f;
        deg_dinv[i] = rsqrtf(deg_dinv[i]);  // deg >= 1 always
    }
}

__global__ void scat_k(const int* __restrict__ ei, const float* __restrict__ ew,
                       int* fill, int* csrc, float* cw, int E) {
    int e = blockIdx.x * 256 + threadIdx.x;
    if (e < E) {
        int dst = ei[E + e];
        int pos = atomicAdd(&fill[dst], 1);
        csrc[pos] = ei[e];
        cw[pos] = ew[e];
    }
}

__global__ void coef_k(const int* __restrict__ rp, const int* __restrict__ csrc,
                       float* cw, const float* __restrict__ dinv, int N) {
    int i = blockIdx.x * 256 + threadIdx.x;
    if (i < N) {
        float di = dinv[i];
        int end = rp[i + 1];
        for (int s = rp[i]; s < end; ++s)
            cw[s] = dinv[csrc[s]] * cw[s] * di;
    }
}

// ---------------- GEMM: out[N,128] = A[N,K] @ W[K,128] (all fp32) ----------------
// MODE 0: A = x (fp32, K=128).  MODE 1: A = gathered [poi|cat|feat3], K=403.
template <int MODE>
__launch_bounds__(256)
__global__ void gemm_k(const float* __restrict__ x,
                       const int* __restrict__ poi_ids, const int* __restrict__ cat_ids,
                       const float* __restrict__ feat3,
                       const float* __restrict__ poi_emb, const float* __restrict__ cat_emb,
                       const float* __restrict__ W,
                       float* __restrict__ out, int N, int K) {
    __shared__ __align__(16) float AsT[32][68];   // [kk][row], stride 68 (16B-aligned rows)
    __shared__ __align__(16) float Ws[32][128];
    int tid = threadIdx.x;
    int tx = tid & 31, ty = tid >> 5;   // tx -> 4 cols, ty -> 8 rows
    int i0 = blockIdx.x * 64;
    float4 acc[8];
    #pragma unroll
    for (int r = 0; r < 8; ++r) acc[r] = make_float4(0.f, 0.f, 0.f, 0.f);

    int nchunk = (K + 31) >> 5;
    for (int ch = 0; ch < nchunk; ++ch) {
        int k0 = ch << 5;
        #pragma unroll
        for (int it = 0; it < 8; ++it) {
            int idx = tid + it * 256;         // 0..2047
            int kk = idx & 31, r = idx >> 5;
            int i = i0 + r, k = k0 + kk;
            float v = 0.f;
            if (i < N && k < K) {
                if (MODE == 0) v = x[(size_t)i * 128 + k];
                else {
                    if (k < 300)      v = poi_emb[(size_t)poi_ids[i] * 300 + k];
                    else if (k < 400) v = cat_emb[(size_t)cat_ids[i] * 100 + (k - 300)];
                    else              v = feat3[(size_t)i * 3 + (k - 400)];
                }
            }
            AsT[kk][r] = v;
        }
        #pragma unroll
        for (int it = 0; it < 4; ++it) {
            int idx = tid + it * 256;         // 0..1023 float4s
            int c4 = idx & 31, kk = idx >> 5;
            int k = k0 + kk;
            float4 wv = make_float4(0.f, 0.f, 0.f, 0.f);
            if (k < K) wv = *(const float4*)&W[(size_t)k * 128 + c4 * 4];
            *(float4*)&Ws[kk][c4 * 4] = wv;
        }
        __syncthreads();
        #pragma unroll
        for (int kk = 0; kk < 32; ++kk) {
            float4 w = *(const float4*)&Ws[kk][tx * 4];
            const float* ap = &AsT[kk][ty * 8];
            float4 a0 = *(const float4*)ap;
            float4 a1 = *(const float4*)(ap + 4);
            float av;
            av = a0.x; acc[0].x += av * w.x; acc[0].y += av * w.y; acc[0].z += av * w.z; acc[0].w += av * w.w;
            av = a0.y; acc[1].x += av * w.x; acc[1].y += av * w.y; acc[1].z += av * w.z; acc[1].w += av * w.w;
            av = a0.z; acc[2].x += av * w.x; acc[2].y += av * w.y; acc[2].z += av * w.z; acc[2].w += av * w.w;
            av = a0.w; acc[3].x += av * w.x; acc[3].y += av * w.y; acc[3].z += av * w.z; acc[3].w += av * w.w;
            av = a1.x; acc[4].x += av * w.x; acc[4].y += av * w.y; acc[4].z += av * w.z; acc[4].w += av * w.w;
            av = a1.y; acc[5].x += av * w.x; acc[5].y += av * w.y; acc[5].z += av * w.z; acc[5].w += av * w.w;
            av = a1.z; acc[6].x += av * w.x; acc[6].y += av * w.y; acc[6].z += av * w.z; acc[6].w += av * w.w;
            av = a1.w; acc[7].x += av * w.x; acc[7].y += av * w.y; acc[7].z += av * w.z; acc[7].w += av * w.w;
        }
        __syncthreads();
    }
    #pragma unroll
    for (int r = 0; r < 8; ++r) {
        int i = i0 + ty * 8 + r;
        if (i < N) *(float4*)&out[(size_t)i * 128 + tx * 4] = acc[r];
    }
}

// ---------------- aggregation: g[dst,:] = sum coef * xw[src,:] + bias ----------------
// one wave per node, 128 channels (float2/lane); wave-uniform slot index ->
// scalar csrc/cw loads; unroll x4 -> 4 independent 512B gathers in flight.
// FUSE==1: write leaky(acc+bias) (input layer, replaces separate leaky pass).
template <int FUSE>
__launch_bounds__(256)
__global__ void agg_k(const float* __restrict__ xw, const int* __restrict__ rp,
                      const int* __restrict__ csrc, const float* __restrict__ cw,
                      const float* __restrict__ bias, float* __restrict__ g, int N) {
    int wave = threadIdx.x >> 6, lane = threadIdx.x & 63;
    int node = blockIdx.x * 4 + wave;
    if (node >= N) return;
    int s = __builtin_amdgcn_readfirstlane(rp[node]);
    int end = __builtin_amdgcn_readfirstlane(rp[node + 1]);
    int c = lane * 2;
    float ax = 0.f, ay = 0.f;
    for (; s + 4 <= end; s += 4) {
        int i0 = csrc[s], i1 = csrc[s + 1], i2 = csrc[s + 2], i3 = csrc[s + 3];
        float w0 = cw[s], w1 = cw[s + 1], w2 = cw[s + 2], w3 = cw[s + 3];
        float2 v0 = *(const float2*)&xw[(size_t)i0 * 128 + c];
        float2 v1 = *(const float2*)&xw[(size_t)i1 * 128 + c];
        float2 v2 = *(const float2*)&xw[(size_t)i2 * 128 + c];
        float2 v3 = *(const float2*)&xw[(size_t)i3 * 128 + c];
        ax += w0 * v0.x + w1 * v1.x + w2 * v2.x + w3 * v3.x;
        ay += w0 * v0.y + w1 * v1.y + w2 * v2.y + w3 * v3.y;
    }
    for (; s < end; ++s) {
        int i0 = csrc[s];
        float w0 = cw[s];
        float2 v0 = *(const float2*)&xw[(size_t)i0 * 128 + c];
        ax += w0 * v0.x;
        ay += w0 * v0.y;
    }
    float2 b = *(const float2*)&bias[c];
    ax += b.x; ay += b.y;
    float2 o;
    if (FUSE == 1) { o.x = leaky01(ax); o.y = leaky01(ay); }
    else           { o.x = ax;          o.y = ay; }
    *(float2*)&g[(size_t)node * 128 + c] = o;
}

// ---------------- GraphNorm moments (float4 streaming) ----------------
__global__ void moments_k(const float* __restrict__ g, float* mom, int n32) {
    __shared__ float s1s[256][4], s2s[256][4];
    int tid = threadIdx.x;
    long long T = (long long)gridDim.x * 256;
    float a1[4] = {0.f, 0.f, 0.f, 0.f}, a2[4] = {0.f, 0.f, 0.f, 0.f};
    const float4* g4 = (const float4*)g;
    for (long long idx = (long long)blockIdx.x * 256 + tid; idx < n32; idx += T) {
        float4 v = g4[idx];
        a1[0] += v.x; a2[0] += v.x * v.x;
        a1[1] += v.y; a2[1] += v.y * v.y;
        a1[2] += v.z; a2[2] += v.z * v.z;
        a1[3] += v.w; a2[3] += v.w * v.w;
    }
    #pragma unroll
    for (int j = 0; j < 4; ++j) { s1s[tid][j] = a1[j]; s2s[tid][j] = a2[j]; }
    __syncthreads();
    if (tid < 32) {
        float r1[4] = {0.f, 0.f, 0.f, 0.f}, r2[4] = {0.f, 0.f, 0.f, 0.f};
        for (int t = tid; t < 256; t += 32) {
            #pragma unroll
            for (int j = 0; j < 4; ++j) { r1[j] += s1s[t][j]; r2[j] += s2s[t][j]; }
        }
        // channel of (t,j) = (4t+j) & 127; for t=tid+32k this is (4*tid+j)
        #pragma unroll
        for (int j = 0; j < 4; ++j) {
            atomicAdd(&mom[4 * tid + j], r1[j]);
            atomicAdd(&mom[128 + 4 * tid + j], r2[j]);
        }
    }
}

// x += leaky( gamma*rsqrt(var+eps)*(g - alpha*mean) + beta )   (float4 streaming)
__global__ void normresid_k(float* __restrict__ x, const float* __restrict__ g,
                            const float* __restrict__ mom,
                            const float* __restrict__ gamma, const float* __restrict__ beta,
                            const float* __restrict__ alpha, int n32, int N) {
    __shared__ float sc[128], sh[128];
    int tid = threadIdx.x;
    if (tid < 128) {
        float m = mom[tid] / (float)N;
        float a = alpha[tid];
        float var = mom[128 + tid] / (float)N - 2.f * a * m * m + a * a * m * m;
        float s = gamma[tid] * rsqrtf(var + 1e-5f);
        sc[tid] = s;
        sh[tid] = beta[tid] - s * a * m;
    }
    __syncthreads();
    const float4* g4 = (const float4*)g;
    float4* x4 = (float4*)x;
    for (long long idx = (long long)blockIdx.x * 256 + tid; idx < n32;
         idx += (long long)gridDim.x * 256) {
        int c0 = (int)((idx * 4) & 127);
        float4 gv = g4[idx];
        float4 xv = x4[idx];
        xv.x += leaky01(sc[c0] * gv.x + sh[c0]);
        xv.y += leaky01(sc[c0 + 1] * gv.y + sh[c0 + 1]);
        xv.z += leaky01(sc[c0 + 2] * gv.z + sh[c0 + 2]);
        xv.w += leaky01(sc[c0 + 3] * gv.w + sh[c0 + 3]);
        x4[idx] = xv;
    }
}

// ---------------- GAT pieces ----------------
__global__ void alar_k(const float* __restrict__ xw, const float* __restrict__ asrc,
                       const float* __restrict__ adst, float* al, float* ar, int N) {
    __shared__ float ls[128], ld[128];
    int tid = threadIdx.x;
    if (tid < 128) { ls[tid] = asrc[tid]; ld[tid] = adst[tid]; }
    __syncthreads();
    int i = blockIdx.x * 256 + tid;
    if (i >= N) return;
    const float* row = xw + (size_t)i * 128;
    float a = 0.f, b = 0.f;
    #pragma unroll 4
    for (int c = 0; c < 128; c += 4) {
        float4 v = *(const float4*)(row + c);
        a += v.x * ls[c] + v.y * ls[c + 1] + v.z * ls[c + 2] + v.w * ls[c + 3];
        b += v.x * ld[c] + v.y * ld[c + 1] + v.z * ld[c + 2] + v.w * ld[c + 3];
    }
    al[i] = a; ar[i] = b;
}

__global__ void att_k(const float* __restrict__ al, const float* __restrict__ ar,
                      const int* __restrict__ rp, const int* __restrict__ csrc,
                      float* att, int N) {
    int tid = threadIdx.x;
    int wave = tid >> 6, lane = tid & 63;
    int node = blockIdx.x * 4 + wave;
    if (node >= N) return;
    int start = rp[node], end = rp[node + 1];
    float ari = ar[node];
    float m = -1e30f;
    for (int s = start + lane; s < end; s += 64) {
        float e = al[csrc[s]] + ari; e = e > 0.f ? e : 0.2f * e;
        m = fmaxf(m, e);
    }
    #pragma unroll
    for (int off = 32; off; off >>= 1) m = fmaxf(m, __shfl_xor(m, off));
    float dsum = 0.f;
    for (int s = start + lane; s < end; s += 64) {
        float e = al[csrc[s]] + ari; e = e > 0.f ? e : 0.2f * e;
        dsum += __expf(e - m);
    }
    #pragma unroll
    for (int off = 32; off; off >>= 1) dsum += __shfl_xor(dsum, off);
    float inv = 1.f / dsum;
    for (int s = start + lane; s < end; s += 64) {
        float e = al[csrc[s]] + ari; e = e > 0.f ? e : 0.2f * e;
        att[s] = __expf(e - m) * inv;
    }
}

// ---------------- output conv + FC head ----------------
__global__ void ydot_k(const float* __restrict__ x, const float* __restrict__ Wout,
                       float* yv, int N) {
    __shared__ float w[128];
    int tid = threadIdx.x;
    if (tid < 128) w[tid] = Wout[tid];
    __syncthreads();
    int i = blockIdx.x * 256 + tid;
    if (i >= N) return;
    const float* row = x + (size_t)i * 128;
    float acc = 0.f;
    #pragma unroll 4
    for (int c = 0; c < 128; c += 4) {
        float4 v = *(const float4*)(row + c);
        acc += v.x * w[c] + v.y * w[c + 1] + v.z * w[c + 2] + v.w * w[c + 3];
    }
    yv[i] = acc;
}

__global__ void aggs_k(const float* __restrict__ yv, const int* __restrict__ rp,
                       const int* __restrict__ csrc, const float* __restrict__ cw,
                       const float* __restrict__ b_out, float* xs, int N) {
    int i = blockIdx.x * 256 + threadIdx.x;
    if (i >= N) return;
    float acc = 0.f;
    int end = rp[i + 1];
    for (int s = rp[i]; s < end; ++s) acc += cw[s] * yv[csrc[s]];
    acc += b_out[0];
    xs[i] = leaky01(acc);
}

__global__ void fc1_k(const float* __restrict__ xs, const float* __restrict__ W1,
                      float* hacc, int N) {
    __shared__ float sd[256];
    int tid = threadIdx.x;
    int j = tid & 127, half = tid >> 7;
    int r0 = blockIdx.x * 256;
    float acc = 0.f;
    for (int rr = half; rr < 256; rr += 2) {
        int r = r0 + rr;
        if (r < N) acc += xs[r] * W1[(size_t)r * 128 + j];
    }
    sd[tid] = acc;
    __syncthreads();
    if (tid < 128) atomicAdd(&hacc[tid], sd[tid] + sd[tid + 128]);
}

__global__ void fc2_k(const float* __restrict__ hacc, const float* __restrict__ b1,
                      const float* __restrict__ W2, const float* __restrict__ b2v,
                      float* out, int P) {
    __shared__ float hs[128];
    int tid = threadIdx.x;
    if (tid < 128) {
        float h = hacc[tid] + b1[tid];
        hs[tid] = h > 0.f ? h : 0.f;
    }
    __syncthreads();
    int p = blockIdx.x * 256 + tid;
    if (p >= P) return;
    float acc = 0.f;
    #pragma unroll 8
    for (int j = 0; j < 128; ++j) acc += hs[j] * W2[(size_t)j * P + p];
    acc += b2v[p];
    out[p] = acc > 0.f ? acc : 0.f;
}

// ---------------- launcher ----------------
extern "C" void kernel_launch(void* const* d_in, const int* in_sizes, int n_in,
                              void* d_out, int out_size, void* d_ws, size_t ws_size,
                              hipStream_t stream) {
    const int*   poi_ids  = (const int*)d_in[0];
    const int*   cat_ids  = (const int*)d_in[1];
    const float* feat3    = (const float*)d_in[2];
    const int*   ei       = (const int*)d_in[3];
    const float* ew       = (const float*)d_in[4];
    const float* poi_emb  = (const float*)d_in[5];
    const float* cat_emb  = (const float*)d_in[6];
    const float* Win      = (const float*)d_in[7];
    const float* b_in     = (const float*)d_in[8];
    const float* gcn_W    = (const float*)d_in[9];
    const float* gcn_b    = (const float*)d_in[10];
    const float* gn_gamma = (const float*)d_in[11];
    const float* gn_beta  = (const float*)d_in[12];
    const float* gn_alpha = (const float*)d_in[13];
    const float* gat_W    = (const float*)d_in[14];
    const float* gat_asrc = (const float*)d_in[15];
    const float* gat_adst = (const float*)d_in[16];
    const float* gat_b    = (const float*)d_in[17];
    const float* Wout     = (const float*)d_in[18];
    const float* b_out    = (const float*)d_in[19];
    const float* fc_W1    = (const float*)d_in[20];
    const float* fc_b1    = (const float*)d_in[21];
    const float* fc_W2    = (const float*)d_in[22];
    const float* fc_b2    = (const float*)d_in[23];

    const int N = in_sizes[0];
    const int E = in_sizes[4];
    const int P = out_size;
    const int TOT = E + N;
    const int n128 = N * 128;
    const int n32 = n128 / 4;   // N*128 divisible by 4

    // workspace carve (256B aligned)
    char* w = (char*)d_ws;
    size_t off = 0;
    auto take = [&](size_t bytes) -> char* {
        char* p = w + off;
        off = (off + bytes + 255) & ~(size_t)255;
        return p;
    };
    float* x    = (float*)take((size_t)n128 * 4);
    float* g    = (float*)take((size_t)n128 * 4);
    float* xw   = (float*)take((size_t)n128 * 4);
    int*   rp   = (int*)take((size_t)(N + 1) * 4);
    int*   cnt  = (int*)take((size_t)N * 4);
    int*   fill = (int*)take((size_t)N * 4);
    float* dinv = (float*)take((size_t)N * 4);
    int*   csrc = (int*)take((size_t)TOT * 4);
    float* cw   = (float*)take((size_t)TOT * 4);
    float* att  = (float*)take((size_t)TOT * 4);
    float* al   = (float*)take((size_t)N * 4);
    float* ar   = (float*)take((size_t)N * 4);
    float* yv   = (float*)take((size_t)N * 4);
    float* xs   = (float*)take((size_t)N * 4);
    float* mom  = (float*)take((size_t)(10 * 256 + 128) * 4);  // 10 graphnorm slots + hacc
    float* hacc = mom + 10 * 256;

    const int gN    = (N + 255) / 256;
    const int gE    = (E + 255) / 256;
    const int gGEMM = (N + 63) / 64;
    const int gAGG  = (N + 3) / 4;
    const int gP    = (P + 255) / 256;

    hipMemsetAsync(mom, 0, (size_t)(10 * 256 + 128) * 4, stream);

    // CSR build
    init_k<<<gN, 256, 0, stream>>>(cnt, dinv, N);              // dinv holds deg for now
    count_k<<<gE, 256, 0, stream>>>(ei, ew, cnt, dinv, E);
    scan_k<<<1, 1024, 0, stream>>>(cnt, rp, N);
    post_k<<<gN, 256, 0, stream>>>(rp, fill, csrc, cw, dinv, N);  // deg -> dinv in-place
    scat_k<<<gE, 256, 0, stream>>>(ei, ew, fill, csrc, cw, E);
    coef_k<<<gN, 256, 0, stream>>>(rp, csrc, cw, dinv, N);

    // input GCN conv: feat @ Win -> agg(+leaky fused) -> x
    gemm_k<1><<<gGEMM, 256, 0, stream>>>(nullptr, poi_ids, cat_ids, feat3, poi_emb, cat_emb,
                                         Win, xw, N, 403);
    agg_k<1><<<gAGG, 256, 0, stream>>>(xw, rp, csrc, cw, b_in, x, N);

    // 5 GcnUnits: (GCNConv -> GraphNorm -> leaky -> +x), (GATConv -> GraphNorm -> leaky -> +x)
    for (int l = 0; l < 5; ++l) {
        // GCN half
        gemm_k<0><<<gGEMM, 256, 0, stream>>>(x, nullptr, nullptr, nullptr, nullptr, nullptr,
                                             gcn_W + (size_t)l * 128 * 128, xw, N, 128);
        agg_k<0><<<gAGG, 256, 0, stream>>>(xw, rp, csrc, cw, gcn_b + l * 128, g, N);
        moments_k<<<240, 256, 0, stream>>>(g, mom + (2 * l) * 256, n32);
        normresid_k<<<1024, 256, 0, stream>>>(x, g, mom + (2 * l) * 256,
                                              gn_gamma + l * 128, gn_beta + l * 128,
                                              gn_alpha + l * 128, n32, N);
        // GAT half
        gemm_k<0><<<gGEMM, 256, 0, stream>>>(x, nullptr, nullptr, nullptr, nullptr, nullptr,
                                             gat_W + (size_t)l * 128 * 128, xw, N, 128);
        alar_k<<<gN, 256, 0, stream>>>(xw, gat_asrc + l * 128, gat_adst + l * 128, al, ar, N);
        att_k<<<(N + 3) / 4, 256, 0, stream>>>(al, ar, rp, csrc, att, N);
        agg_k<0><<<gAGG, 256, 0, stream>>>(xw, rp, csrc, att, gat_b + l * 128, g, N);
        moments_k<<<240, 256, 0, stream>>>(g, mom + (2 * l + 1) * 256, n32);
        normresid_k<<<1024, 256, 0, stream>>>(x, g, mom + (2 * l + 1) * 256,
                                              gn_gamma + l * 128, gn_beta + l * 128,
                                              gn_alpha + l * 128, n32, N);
    }

    // output conv (C -> 1) + leaky
    ydot_k<<<gN, 256, 0, stream>>>(x, Wout, yv, N);
    aggs_k<<<gN, 256, 0, stream>>>(yv, rp, csrc, cw, b_out, xs, N);

    // FC head
    fc1_k<<<(N + 255) / 256, 256, 0, stream>>>(xs, fc_W1, hacc, N);
    fc2_k<<<gP, 256, 0, stream>>>(hacc, fc_b1, fc_W2, fc_b2, (float*)d_out, P);
}

// Round 4
// 1698.831 us; speedup vs baseline: 2.2263x; 1.3553x over previous
//
#include <hip/hip_runtime.h>

typedef unsigned short ushort_t;
typedef __attribute__((ext_vector_type(8))) short short8v;
typedef __attribute__((ext_vector_type(4))) float floatx4;

__device__ __forceinline__ float b2f(ushort_t u) {
    unsigned int x = ((unsigned int)u) << 16;
    float f; __builtin_memcpy(&f, &x, 4); return f;
}
__device__ __forceinline__ ushort_t f2b(float f) {
    unsigned int x; __builtin_memcpy(&x, &f, 4);
    unsigned int lsb = (x >> 16) & 1u;
    x += 0x7fffu + lsb;
    return (ushort_t)(x >> 16);
}
__device__ __forceinline__ float leaky01(float v) { return v > 0.f ? v : 0.01f * v; }

// ---------------- CSR build ----------------
__global__ void init_k(int* cnt, float* deg, int N) {
    int i = blockIdx.x * 256 + threadIdx.x;
    if (i < N) { cnt[i] = 1; deg[i] = 1.0f; }  // self-loop: count 1, weight 1
}

__global__ void count_k(const int* __restrict__ ei, const float* __restrict__ ew,
                        int* cnt, float* deg, int E) {
    int e = blockIdx.x * 256 + threadIdx.x;
    if (e < E) {
        int dst = ei[E + e];
        atomicAdd(&cnt[dst], 1);
        atomicAdd(&deg[dst], ew[e]);
    }
}

__launch_bounds__(1024)
__global__ void scan_k(const int* __restrict__ cnt, int* rp, int n) {
    __shared__ int wsum[16];
    int tid = threadIdx.x; int lane = tid & 63, wid = tid >> 6;
    int base = 0;
    for (int start = 0; start < n; start += 4096) {
        int v[4]; int s = 0;
        #pragma unroll
        for (int j = 0; j < 4; ++j) {
            int i = start + tid * 4 + j;
            v[j] = (i < n) ? cnt[i] : 0; s += v[j];
        }
        int sc = s;
        #pragma unroll
        for (int off = 1; off < 64; off <<= 1) {
            int t = __shfl_up(sc, off);
            if (lane >= off) sc += t;
        }
        if (lane == 63) wsum[wid] = sc;
        __syncthreads();
        if (wid == 0) {
            int ws = (lane < 16) ? wsum[lane] : 0;
            #pragma unroll
            for (int off = 1; off < 16; off <<= 1) {
                int t = __shfl_up(ws, off);
                if (lane >= off) ws += t;
            }
            if (lane < 16) wsum[lane] = ws;
        }
        __syncthreads();
        int wbase = (wid > 0) ? wsum[wid - 1] : 0;
        int excl = base + wbase + (sc - s);
        #pragma unroll
        for (int j = 0; j < 4; ++j) {
            int i = start + tid * 4 + j;
            if (i < n) rp[i] = excl;
            excl += v[j];
        }
        int total = wsum[15];
        __syncthreads();
        base += total;
    }
    if (tid == 0) rp[n] = base;
}

__global__ void post_k(const int* __restrict__ rp, int* fill, int* csrc, float* cw,
                       float* deg_dinv, int N) {
    int i = blockIdx.x * 256 + threadIdx.x;
    if (i < N) {
        int p = rp[i];
        fill[i] = p + 1;          // slot p reserved for self-loop
        csrc[p] = i;
        cw[p] = 1.0f;
        deg_dinv[i] = rsqrtf(deg_dinv[i]);  // deg >= 1 always
    }
}

__global__ void scat_k(const int* __restrict__ ei, const float* __restrict__ ew,
                       int* fill, int* csrc, float* cw, int E) {
    int e = blockIdx.x * 256 + threadIdx.x;
    if (e < E) {
        int dst = ei[E + e];
        int pos = atomicAdd(&fill[dst], 1);
        csrc[pos] = ei[e];
        cw[pos] = ew[e];
    }
}

__global__ void coef_k(const int* __restrict__ rp, const int* __restrict__ csrc,
                       float* cw, const float* __restrict__ dinv, int N) {
    int i = blockIdx.x * 256 + threadIdx.x;
    if (i < N) {
        float di = dinv[i];
        int end = rp[i + 1];
        for (int s = rp[i]; s < end; ++s)
            cw[s] = dinv[csrc[s]] * cw[s] * di;
    }
}

// ---------------- weight prep: transpose + cast to bf16 ----------------
// wt[l][n][k] (l<5: gcn_W[l], else gat_W[l-5]); wtin[n][k] from Win rows 0..299 (pad to 320)
__global__ void prep_w(const float* __restrict__ gcn_W, const float* __restrict__ gat_W,
                       const float* __restrict__ Win, ushort_t* __restrict__ wt,
                       ushort_t* __restrict__ wtin) {
    int idx = blockIdx.x * 256 + threadIdx.x;
    if (idx < 10 * 16384) {
        int l = idx >> 14, r = idx & 16383;
        int n = r >> 7, k = r & 127;
        const float* src = (l < 5) ? (gcn_W + l * 16384) : (gat_W + (l - 5) * 16384);
        wt[idx] = f2b(src[k * 128 + n]);
    } else {
        int idx2 = idx - 10 * 16384;
        if (idx2 < 128 * 320) {
            int n = idx2 / 320, k = idx2 - n * 320;
            wtin[idx2] = f2b(k < 300 ? Win[k * 128 + n] : 0.f);
        }
    }
}

// ---------------- cat projection: cp[400][128] = cat_emb @ Win[300:400] ----------------
__global__ void cat_proj_k(const float* __restrict__ ce, const float* __restrict__ Win,
                           float* __restrict__ cp) {
    __shared__ float row[100];
    int r = blockIdx.x, tid = threadIdx.x;   // 128 threads
    if (tid < 100) row[tid] = ce[r * 100 + tid];
    __syncthreads();
    float acc = 0.f;
    #pragma unroll 4
    for (int k = 0; k < 100; ++k) acc += row[k] * Win[(300 + k) * 128 + tid];
    cp[r * 128 + tid] = acc;
}

// ---------------- poi projection: pp[POI_LEN][128] bf16 = poi_emb @ Win[0:300] (MFMA) ---
__launch_bounds__(256)
__global__ void poi_gemm(const float* __restrict__ pe, const ushort_t* __restrict__ wtin,
                         ushort_t* __restrict__ pp, int P) {
    __shared__ __align__(16) ushort_t As[64 * 328];   // 64 rows x 320 k (pad stride 328)
    int tid = threadIdx.x;
    int wid = tid >> 6, lane = tid & 63;
    int r0 = blockIdx.x * 64;
    // stage 64 x 320 bf16 (cast from fp32, zero k>=300 / row>=P)
    #pragma unroll
    for (int p = 0; p < 80; ++p) {
        int idx = tid + p * 256;       // 0..20479
        int row = idx / 320, k = idx - row * 320;
        float v = 0.f;
        if (k < 300 && (r0 + row) < P) v = pe[(size_t)(r0 + row) * 300 + k];
        As[row * 328 + k] = f2b(v);
    }
    __syncthreads();
    int m = lane & 15, q = lane >> 4;
    short8v af[10];
    #pragma unroll
    for (int kc = 0; kc < 10; ++kc)
        af[kc] = *(const short8v*)&As[(wid * 16 + m) * 328 + kc * 32 + q * 8];
    #pragma unroll
    for (int ct = 0; ct < 8; ++ct) {
        const ushort_t* wr = wtin + (size_t)(ct * 16 + m) * 320 + q * 8;
        floatx4 acc = {0.f, 0.f, 0.f, 0.f};
        #pragma unroll
        for (int kc = 0; kc < 10; ++kc) {
            short8v b = *(const short8v*)(wr + kc * 32);
            acc = __builtin_amdgcn_mfma_f32_16x16x32_bf16(af[kc], b, acc, 0, 0, 0);
        }
        int col = ct * 16 + m;
        #pragma unroll
        for (int rg = 0; rg < 4; ++rg) {
            int row = r0 + wid * 16 + q * 4 + rg;
            if (row < P) pp[(size_t)row * 128 + col] = f2b(acc[rg]);
        }
    }
}

// ---------------- layer GEMM (MFMA): xw[N][128] bf16 = x_bf @ W (wt = W^T bf16) --------
__launch_bounds__(256)
__global__ void gemm_mfma(const ushort_t* __restrict__ xb, const ushort_t* __restrict__ wt,
                          ushort_t* __restrict__ xw, int N) {
    __shared__ __align__(16) ushort_t As[64 * 136];
    int tid = threadIdx.x;
    int wid = tid >> 6, lane = tid & 63;
    int r0 = blockIdx.x * 64;
    // stage A: 64 rows x 128 bf16 (xb padded to multiple of 64 rows)
    #pragma unroll
    for (int p = 0; p < 4; ++p) {
        int idx = tid + p * 256;       // 1024 chunks of 8 bf16
        int row = idx >> 4, c8 = idx & 15;
        short8v v = *(const short8v*)&xb[(size_t)(r0 + row) * 128 + c8 * 8];
        *(short8v*)&As[row * 136 + c8 * 8] = v;
    }
    __syncthreads();
    int m = lane & 15, q = lane >> 4;
    const int ar = (wid * 16 + m) * 136 + q * 8;
    short8v a0 = *(const short8v*)&As[ar];
    short8v a1 = *(const short8v*)&As[ar + 32];
    short8v a2 = *(const short8v*)&As[ar + 64];
    short8v a3 = *(const short8v*)&As[ar + 96];
    #pragma unroll
    for (int ct = 0; ct < 8; ++ct) {
        const ushort_t* wr = wt + (size_t)(ct * 16 + m) * 128 + q * 8;
        short8v b0 = *(const short8v*)(wr);
        short8v b1 = *(const short8v*)(wr + 32);
        short8v b2 = *(const short8v*)(wr + 64);
        short8v b3 = *(const short8v*)(wr + 96);
        floatx4 acc = {0.f, 0.f, 0.f, 0.f};
        acc = __builtin_amdgcn_mfma_f32_16x16x32_bf16(a0, b0, acc, 0, 0, 0);
        acc = __builtin_amdgcn_mfma_f32_16x16x32_bf16(a1, b1, acc, 0, 0, 0);
        acc = __builtin_amdgcn_mfma_f32_16x16x32_bf16(a2, b2, acc, 0, 0, 0);
        acc = __builtin_amdgcn_mfma_f32_16x16x32_bf16(a3, b3, acc, 0, 0, 0);
        int col = ct * 16 + m;
        #pragma unroll
        for (int rg = 0; rg < 4; ++rg) {
            int row = r0 + wid * 16 + q * 4 + rg;
            if (row < N) xw[(size_t)row * 128 + col] = f2b(acc[rg]);
        }
    }
}

// ---------------- combine: xw0 = pp[poi_id] + cp[cat_id] + feat3 @ Win[400:403] --------
__global__ void combine_k(const ushort_t* __restrict__ pp, const float* __restrict__ cp,
                          const int* __restrict__ poi_ids, const int* __restrict__ cat_ids,
                          const float* __restrict__ feat3, const float* __restrict__ Win,
                          ushort_t* __restrict__ xw, int N) {
    __shared__ float wf0[128], wf1[128], wf2[128];
    int tid = threadIdx.x;
    if (tid < 128) {
        wf0[tid] = Win[400 * 128 + tid];
        wf1[tid] = Win[401 * 128 + tid];
        wf2[tid] = Win[402 * 128 + tid];
    }
    __syncthreads();
    int node = blockIdx.x * 2 + (tid >> 7);
    int c = tid & 127;
    if (node >= N) return;
    int pid = poi_ids[node], cid = cat_ids[node];
    float f0 = feat3[node * 3], f1 = feat3[node * 3 + 1], f2 = feat3[node * 3 + 2];
    float v = b2f(pp[(size_t)pid * 128 + c]) + cp[cid * 128 + c]
            + f0 * wf0[c] + f1 * wf1[c] + f2 * wf2[c];
    xw[(size_t)node * 128 + c] = f2b(v);
}

// ---------------- aggregation: g[dst,:] = sum coef * xw[src,:] + bias (xw bf16) --------
// FUSE==1: write leaky(acc+bias) to g(=x fp32) AND xb (bf16 copy).
template <int FUSE>
__launch_bounds__(256)
__global__ void agg_k(const ushort_t* __restrict__ xw, const int* __restrict__ rp,
                      const int* __restrict__ csrc, const float* __restrict__ cw,
                      const float* __restrict__ bias, float* __restrict__ g,
                      ushort_t* __restrict__ xb, int N) {
    int wave = threadIdx.x >> 6, lane = threadIdx.x & 63;
    int node = blockIdx.x * 4 + wave;
    if (node >= N) return;
    int s = __builtin_amdgcn_readfirstlane(rp[node]);
    int end = __builtin_amdgcn_readfirstlane(rp[node + 1]);
    int c = lane * 2;
    float ax = 0.f, ay = 0.f;
    for (; s + 4 <= end; s += 4) {
        int i0 = csrc[s], i1 = csrc[s + 1], i2 = csrc[s + 2], i3 = csrc[s + 3];
        float w0 = cw[s], w1 = cw[s + 1], w2 = cw[s + 2], w3 = cw[s + 3];
        ushort2 u0 = *(const ushort2*)&xw[(size_t)i0 * 128 + c];
        ushort2 u1 = *(const ushort2*)&xw[(size_t)i1 * 128 + c];
        ushort2 u2 = *(const ushort2*)&xw[(size_t)i2 * 128 + c];
        ushort2 u3 = *(const ushort2*)&xw[(size_t)i3 * 128 + c];
        ax += w0 * b2f(u0.x) + w1 * b2f(u1.x) + w2 * b2f(u2.x) + w3 * b2f(u3.x);
        ay += w0 * b2f(u0.y) + w1 * b2f(u1.y) + w2 * b2f(u2.y) + w3 * b2f(u3.y);
    }
    for (; s < end; ++s) {
        int i0 = csrc[s];
        float w0 = cw[s];
        ushort2 u0 = *(const ushort2*)&xw[(size_t)i0 * 128 + c];
        ax += w0 * b2f(u0.x);
        ay += w0 * b2f(u0.y);
    }
    float2 b = *(const float2*)&bias[c];
    ax += b.x; ay += b.y;
    if (FUSE == 1) {
        ax = leaky01(ax); ay = leaky01(ay);
        float2 o; o.x = ax; o.y = ay;
        *(float2*)&g[(size_t)node * 128 + c] = o;
        ushort2 ub; ub.x = f2b(ax); ub.y = f2b(ay);
        *(ushort2*)&xb[(size_t)node * 128 + c] = ub;
    } else {
        float2 o; o.x = ax; o.y = ay;
        *(float2*)&g[(size_t)node * 128 + c] = o;
    }
}

// ---------------- GraphNorm moments (float4 streaming) ----------------
__global__ void moments_k(const float* __restrict__ g, float* mom, int n32) {
    __shared__ float s1s[256][4], s2s[256][4];
    int tid = threadIdx.x;
    long long T = (long long)gridDim.x * 256;
    float a1[4] = {0.f, 0.f, 0.f, 0.f}, a2[4] = {0.f, 0.f, 0.f, 0.f};
    const float4* g4 = (const float4*)g;
    for (long long idx = (long long)blockIdx.x * 256 + tid; idx < n32; idx += T) {
        float4 v = g4[idx];
        a1[0] += v.x; a2[0] += v.x * v.x;
        a1[1] += v.y; a2[1] += v.y * v.y;
        a1[2] += v.z; a2[2] += v.z * v.z;
        a1[3] += v.w; a2[3] += v.w * v.w;
    }
    #pragma unroll
    for (int j = 0; j < 4; ++j) { s1s[tid][j] = a1[j]; s2s[tid][j] = a2[j]; }
    __syncthreads();
    if (tid < 32) {
        float r1[4] = {0.f, 0.f, 0.f, 0.f}, r2[4] = {0.f, 0.f, 0.f, 0.f};
        for (int t = tid; t < 256; t += 32) {
            #pragma unroll
            for (int j = 0; j < 4; ++j) { r1[j] += s1s[t][j]; r2[j] += s2s[t][j]; }
        }
        #pragma unroll
        for (int j = 0; j < 4; ++j) {
            atomicAdd(&mom[4 * tid + j], r1[j]);
            atomicAdd(&mom[128 + 4 * tid + j], r2[j]);
        }
    }
}

// x += leaky( gamma*rsqrt(var+eps)*(g - alpha*mean) + beta ); also write x_bf (bf16)
__global__ void normresid_k(float* __restrict__ x, const float* __restrict__ g,
                            const float* __restrict__ mom,
                            const float* __restrict__ gamma, const float* __restrict__ beta,
                            const float* __restrict__ alpha, ushort_t* __restrict__ xb,
                            int n32, int N) {
    __shared__ float sc[128], sh[128];
    int tid = threadIdx.x;
    if (tid < 128) {
        float m = mom[tid] / (float)N;
        float a = alpha[tid];
        float var = mom[128 + tid] / (float)N - 2.f * a * m * m + a * a * m * m;
        float s = gamma[tid] * rsqrtf(var + 1e-5f);
        sc[tid] = s;
        sh[tid] = beta[tid] - s * a * m;
    }
    __syncthreads();
    const float4* g4 = (const float4*)g;
    float4* x4 = (float4*)x;
    ushort4* xb4 = (ushort4*)xb;
    for (long long idx = (long long)blockIdx.x * 256 + tid; idx < n32;
         idx += (long long)gridDim.x * 256) {
        int c0 = (int)((idx * 4) & 127);
        float4 gv = g4[idx];
        float4 xv = x4[idx];
        xv.x += leaky01(sc[c0] * gv.x + sh[c0]);
        xv.y += leaky01(sc[c0 + 1] * gv.y + sh[c0 + 1]);
        xv.z += leaky01(sc[c0 + 2] * gv.z + sh[c0 + 2]);
        xv.w += leaky01(sc[c0 + 3] * gv.w + sh[c0 + 3]);
        x4[idx] = xv;
        ushort4 ub;
        ub.x = f2b(xv.x); ub.y = f2b(xv.y); ub.z = f2b(xv.z); ub.w = f2b(xv.w);
        xb4[idx] = ub;
    }
}

// ---------------- GAT pieces ----------------
__global__ void alar_k(const ushort_t* __restrict__ xw, const float* __restrict__ asrc,
                       const float* __restrict__ adst, float* al, float* ar, int N) {
    __shared__ float ls[128], ld[128];
    int tid = threadIdx.x;
    if (tid < 128) { ls[tid] = asrc[tid]; ld[tid] = adst[tid]; }
    __syncthreads();
    int i = blockIdx.x * 256 + tid;
    if (i >= N) return;
    const ushort_t* row = xw + (size_t)i * 128;
    float a = 0.f, b = 0.f;
    #pragma unroll 4
    for (int c = 0; c < 128; c += 4) {
        ushort4 u = *(const ushort4*)(row + c);
        float f0 = b2f(u.x), f1 = b2f(u.y), f2 = b2f(u.z), f3 = b2f(u.w);
        a += f0 * ls[c] + f1 * ls[c + 1] + f2 * ls[c + 2] + f3 * ls[c + 3];
        b += f0 * ld[c] + f1 * ld[c + 1] + f2 * ld[c + 2] + f3 * ld[c + 3];
    }
    al[i] = a; ar[i] = b;
}

__global__ void att_k(const float* __restrict__ al, const float* __restrict__ ar,
                      const int* __restrict__ rp, const int* __restrict__ csrc,
                      float* att, int N) {
    int tid = threadIdx.x;
    int wave = tid >> 6, lane = tid & 63;
    int node = blockIdx.x * 4 + wave;
    if (node >= N) return;
    int start = rp[node], end = rp[node + 1];
    float ari = ar[node];
    float m = -1e30f;
    for (int s = start + lane; s < end; s += 64) {
        float e = al[csrc[s]] + ari; e = e > 0.f ? e : 0.2f * e;
        m = fmaxf(m, e);
    }
    #pragma unroll
    for (int off = 32; off; off >>= 1) m = fmaxf(m, __shfl_xor(m, off));
    float dsum = 0.f;
    for (int s = start + lane; s < end; s += 64) {
        float e = al[csrc[s]] + ari; e = e > 0.f ? e : 0.2f * e;
        dsum += __expf(e - m);
    }
    #pragma unroll
    for (int off = 32; off; off >>= 1) dsum += __shfl_xor(dsum, off);
    float inv = 1.f / dsum;
    for (int s = start + lane; s < end; s += 64) {
        float e = al[csrc[s]] + ari; e = e > 0.f ? e : 0.2f * e;
        att[s] = __expf(e - m) * inv;
    }
}

// ---------------- output conv + FC head ----------------
__global__ void ydot_k(const float* __restrict__ x, const float* __restrict__ Wout,
                       float* yv, int N) {
    __shared__ float w[128];
    int tid = threadIdx.x;
    if (tid < 128) w[tid] = Wout[tid];
    __syncthreads();
    int i = blockIdx.x * 256 + tid;
    if (i >= N) return;
    const float* row = x + (size_t)i * 128;
    float acc = 0.f;
    #pragma unroll 4
    for (int c = 0; c < 128; c += 4) {
        float4 v = *(const float4*)(row + c);
        acc += v.x * w[c] + v.y * w[c + 1] + v.z * w[c + 2] + v.w * w[c + 3];
    }
    yv[i] = acc;
}

__global__ void aggs_k(const float* __restrict__ yv, const int* __restrict__ rp,
                       const int* __restrict__ csrc, const float* __restrict__ cw,
                       const float* __restrict__ b_out, float* xs, int N) {
    int i = blockIdx.x * 256 + threadIdx.x;
    if (i >= N) return;
    float acc = 0.f;
    int end = rp[i + 1];
    for (int s = rp[i]; s < end; ++s) acc += cw[s] * yv[csrc[s]];
    acc += b_out[0];
    xs[i] = leaky01(acc);
}

__global__ void fc1_k(const float* __restrict__ xs, const float* __restrict__ W1,
                      float* hacc, int N) {
    __shared__ float sd[256];
    int tid = threadIdx.x;
    int j = tid & 127, half = tid >> 7;
    int r0 = blockIdx.x * 256;
    float acc = 0.f;
    for (int rr = half; rr < 256; rr += 2) {
        int r = r0 + rr;
        if (r < N) acc += xs[r] * W1[(size_t)r * 128 + j];
    }
    sd[tid] = acc;
    __syncthreads();
    if (tid < 128) atomicAdd(&hacc[tid], sd[tid] + sd[tid + 128]);
}

__global__ void fc2_k(const float* __restrict__ hacc, const float* __restrict__ b1,
                      const float* __restrict__ W2, const float* __restrict__ b2v,
                      float* out, int P) {
    __shared__ float hs[128];
    int tid = threadIdx.x;
    if (tid < 128) {
        float h = hacc[tid] + b1[tid];
        hs[tid] = h > 0.f ? h : 0.f;
    }
    __syncthreads();
    int p = blockIdx.x * 256 + tid;
    if (p >= P) return;
    float acc = 0.f;
    #pragma unroll 8
    for (int j = 0; j < 128; ++j) acc += hs[j] * W2[(size_t)j * P + p];
    acc += b2v[p];
    out[p] = acc > 0.f ? acc : 0.f;
}

// ---------------- launcher ----------------
extern "C" void kernel_launch(void* const* d_in, const int* in_sizes, int n_in,
                              void* d_out, int out_size, void* d_ws, size_t ws_size,
                              hipStream_t stream) {
    const int*   poi_ids  = (const int*)d_in[0];
    const int*   cat_ids  = (const int*)d_in[1];
    const float* feat3    = (const float*)d_in[2];
    const int*   ei       = (const int*)d_in[3];
    const float* ew       = (const float*)d_in[4];
    const float* poi_emb  = (const float*)d_in[5];
    const float* cat_emb  = (const float*)d_in[6];
    const float* Win      = (const float*)d_in[7];
    const float* b_in     = (const float*)d_in[8];
    const float* gcn_W    = (const float*)d_in[9];
    const float* gcn_b    = (const float*)d_in[10];
    const float* gn_gamma = (const float*)d_in[11];
    const float* gn_beta  = (const float*)d_in[12];
    const float* gn_alpha = (const float*)d_in[13];
    const float* gat_W    = (const float*)d_in[14];
    const float* gat_asrc = (const float*)d_in[15];
    const float* gat_adst = (const float*)d_in[16];
    const float* gat_b    = (const float*)d_in[17];
    const float* Wout     = (const float*)d_in[18];
    const float* b_out    = (const float*)d_in[19];
    const float* fc_W1    = (const float*)d_in[20];
    const float* fc_b1    = (const float*)d_in[21];
    const float* fc_W2    = (const float*)d_in[22];
    const float* fc_b2    = (const float*)d_in[23];

    const int N = in_sizes[0];
    const int E = in_sizes[4];
    const int POI = in_sizes[5] / 300;   // POI_LEN
    const int P = out_size;
    const int TOT = E + N;
    const int n128 = N * 128;
    const int n32 = n128 / 4;
    const int NPAD = ((N + 63) / 64) * 64;       // row-padded for MFMA staging
    const int PPAD = ((POI + 63) / 64) * 64;

    // workspace carve (256B aligned)
    char* w = (char*)d_ws;
    size_t off = 0;
    auto take = [&](size_t bytes) -> char* {
        char* p = w + off;
        off = (off + bytes + 255) & ~(size_t)255;
        return p;
    };
    float*    x    = (float*)take((size_t)n128 * 4);
    float*    g    = (float*)take((size_t)n128 * 4);
    ushort_t* xb   = (ushort_t*)take((size_t)NPAD * 128 * 2);  // bf16 copy of x
    ushort_t* xw   = (ushort_t*)take((size_t)NPAD * 128 * 2);  // bf16 x@W
    ushort_t* pp   = (ushort_t*)take((size_t)PPAD * 128 * 2);  // poi projection bf16
    float*    cp   = (float*)take((size_t)400 * 128 * 4);      // cat projection
    ushort_t* wt   = (ushort_t*)take((size_t)10 * 16384 * 2);  // layer W^T bf16
    ushort_t* wtin = (ushort_t*)take((size_t)128 * 320 * 2);   // Win[0:300]^T bf16 (padded)
    int*   rp   = (int*)take((size_t)(N + 1) * 4);
    int*   cnt  = (int*)take((size_t)N * 4);
    int*   fill = (int*)take((size_t)N * 4);
    float* dinv = (float*)take((size_t)N * 4);
    int*   csrc = (int*)take((size_t)TOT * 4);
    float* cw   = (float*)take((size_t)TOT * 4);
    float* att  = (float*)take((size_t)TOT * 4);
    float* al   = (float*)take((size_t)N * 4);
    float* ar   = (float*)take((size_t)N * 4);
    float* yv   = (float*)take((size_t)N * 4);
    float* xs   = (float*)take((size_t)N * 4);
    float* mom  = (float*)take((size_t)(10 * 256 + 128) * 4);
    float* hacc = mom + 10 * 256;

    const int gN    = (N + 255) / 256;
    const int gE    = (E + 255) / 256;
    const int gMM   = NPAD / 64;
    const int gPOI  = PPAD / 64;
    const int gAGG  = (N + 3) / 4;
    const int gP    = (P + 255) / 256;

    hipMemsetAsync(mom, 0, (size_t)(10 * 256 + 128) * 4, stream);

    // CSR build
    init_k<<<gN, 256, 0, stream>>>(cnt, dinv, N);
    count_k<<<gE, 256, 0, stream>>>(ei, ew, cnt, dinv, E);
    scan_k<<<1, 1024, 0, stream>>>(cnt, rp, N);
    post_k<<<gN, 256, 0, stream>>>(rp, fill, csrc, cw, dinv, N);
    scat_k<<<gE, 256, 0, stream>>>(ei, ew, fill, csrc, cw, E);
    coef_k<<<gN, 256, 0, stream>>>(rp, csrc, cw, dinv, N);

    // weight prep + input conv
    prep_w<<<(10 * 16384 + 128 * 320 + 255) / 256, 256, 0, stream>>>(gcn_W, gat_W, Win, wt, wtin);
    cat_proj_k<<<400, 128, 0, stream>>>(cat_emb, Win, cp);
    poi_gemm<<<gPOI, 256, 0, stream>>>(poi_emb, wtin, pp, POI);
    combine_k<<<(N + 1) / 2, 256, 0, stream>>>(pp, cp, poi_ids, cat_ids, feat3, Win, xw, N);
    agg_k<1><<<gAGG, 256, 0, stream>>>(xw, rp, csrc, cw, b_in, x, xb, N);

    // 5 GcnUnits
    for (int l = 0; l < 5; ++l) {
        // GCN half
        gemm_mfma<<<gMM, 256, 0, stream>>>(xb, wt + (size_t)l * 16384, xw, N);
        agg_k<0><<<gAGG, 256, 0, stream>>>(xw, rp, csrc, cw, gcn_b + l * 128, g, nullptr, N);
        moments_k<<<240, 256, 0, stream>>>(g, mom + (2 * l) * 256, n32);
        normresid_k<<<1024, 256, 0, stream>>>(x, g, mom + (2 * l) * 256,
                                              gn_gamma + l * 128, gn_beta + l * 128,
                                              gn_alpha + l * 128, xb, n32, N);
        // GAT half
        gemm_mfma<<<gMM, 256, 0, stream>>>(xb, wt + (size_t)(5 + l) * 16384, xw, N);
        alar_k<<<gN, 256, 0, stream>>>(xw, gat_asrc + l * 128, gat_adst + l * 128, al, ar, N);
        att_k<<<(N + 3) / 4, 256, 0, stream>>>(al, ar, rp, csrc, att, N);
        agg_k<0><<<gAGG, 256, 0, stream>>>(xw, rp, csrc, att, gat_b + l * 128, g, nullptr, N);
        moments_k<<<240, 256, 0, stream>>>(g, mom + (2 * l + 1) * 256, n32);
        normresid_k<<<1024, 256, 0, stream>>>(x, g, mom + (2 * l + 1) * 256,
                                              gn_gamma + l * 128, gn_beta + l * 128,
                                              gn_alpha + l * 128, xb, n32, N);
    }

    // output conv (C -> 1) + leaky
    ydot_k<<<gN, 256, 0, stream>>>(x, Wout, yv, N);
    aggs_k<<<gN, 256, 0, stream>>>(yv, rp, csrc, cw, b_out, xs, N);

    // FC head
    fc1_k<<<(N + 255) / 256, 256, 0, stream>>>(xs, fc_W1, hacc, N);
    fc2_k<<<gP, 256, 0, stream>>>(hacc, fc_b1, fc_W2, fc_b2, (float*)d_out, P);
}

// Round 5
// 1580.775 us; speedup vs baseline: 2.3926x; 1.0747x over previous
//
#include <hip/hip_runtime.h>

typedef unsigned short ushort_t;
typedef __attribute__((ext_vector_type(8))) short short8v;
typedef __attribute__((ext_vector_type(4))) float floatx4;

__device__ __forceinline__ float b2f(ushort_t u) {
    unsigned int x = ((unsigned int)u) << 16;
    float f; __builtin_memcpy(&f, &x, 4); return f;
}
__device__ __forceinline__ ushort_t f2b(float f) {
    unsigned int x; __builtin_memcpy(&x, &f, 4);
    unsigned int lsb = (x >> 16) & 1u;
    x += 0x7fffu + lsb;
    return (ushort_t)(x >> 16);
}
__device__ __forceinline__ float leaky01(float v) { return v > 0.f ? v : 0.01f * v; }

// ---------------- CSR build ----------------
__global__ void init_k(int* cnt, int N) {
    int i = blockIdx.x * 256 + threadIdx.x;
    if (i < N) cnt[i] = 1;   // self-loop
}

__global__ void count_k(const int* __restrict__ ei, int* cnt, int E) {
    int e = blockIdx.x * 256 + threadIdx.x;
    if (e < E) atomicAdd(&cnt[ei[E + e]], 1);
}

__launch_bounds__(1024)
__global__ void scan_k(const int* __restrict__ cnt, int* rp, int n) {
    __shared__ int wsum[16];
    int tid = threadIdx.x; int lane = tid & 63, wid = tid >> 6;
    int base = 0;
    for (int start = 0; start < n; start += 4096) {
        int v[4]; int s = 0;
        #pragma unroll
        for (int j = 0; j < 4; ++j) {
            int i = start + tid * 4 + j;
            v[j] = (i < n) ? cnt[i] : 0; s += v[j];
        }
        int sc = s;
        #pragma unroll
        for (int off = 1; off < 64; off <<= 1) {
            int t = __shfl_up(sc, off);
            if (lane >= off) sc += t;
        }
        if (lane == 63) wsum[wid] = sc;
        __syncthreads();
        if (wid == 0) {
            int ws = (lane < 16) ? wsum[lane] : 0;
            #pragma unroll
            for (int off = 1; off < 16; off <<= 1) {
                int t = __shfl_up(ws, off);
                if (lane >= off) ws += t;
            }
            if (lane < 16) wsum[lane] = ws;
        }
        __syncthreads();
        int wbase = (wid > 0) ? wsum[wid - 1] : 0;
        int excl = base + wbase + (sc - s);
        #pragma unroll
        for (int j = 0; j < 4; ++j) {
            int i = start + tid * 4 + j;
            if (i < n) rp[i] = excl;
            excl += v[j];
        }
        int total = wsum[15];
        __syncthreads();
        base += total;
    }
    if (tid == 0) rp[n] = base;
}

// edge record: .x = src (int bits), .y = weight
__global__ void post_k(const int* __restrict__ rp, int* fill, float2* er, int N) {
    int i = blockIdx.x * 256 + threadIdx.x;
    if (i < N) {
        int p = rp[i];
        fill[i] = p + 1;                       // slot p reserved for self-loop
        er[p] = make_float2(__int_as_float(i), 1.0f);
    }
}

__global__ void scat_k(const int* __restrict__ ei, const float* __restrict__ ew,
                       int* fill, float2* er, int E) {
    int e = blockIdx.x * 256 + threadIdx.x;
    if (e < E) {
        int dst = ei[E + e];
        int pos = atomicAdd(&fill[dst], 1);
        er[pos] = make_float2(__int_as_float(ei[e]), ew[e]);
    }
}

// wave per node: dinv[i] = rsqrt(sum of segment weights)
__global__ void deg_k(const int* __restrict__ rp, const float2* __restrict__ er,
                      float* dinv, int N) {
    int wave = threadIdx.x >> 6, lane = threadIdx.x & 63;
    int node = blockIdx.x * 4 + wave;
    if (node >= N) return;
    int s0 = rp[node], end = rp[node + 1];
    float sum = 0.f;
    for (int s = s0 + lane; s < end; s += 64) sum += er[s].y;
    #pragma unroll
    for (int off = 32; off; off >>= 1) sum += __shfl_xor(sum, off);
    if (lane == 0) dinv[node] = rsqrtf(sum);
}

// wave per node: er.y = dinv[src]*w*dinv[dst]
__global__ void coef_k(const int* __restrict__ rp, float2* er,
                       const float* __restrict__ dinv, int N) {
    int wave = threadIdx.x >> 6, lane = threadIdx.x & 63;
    int node = blockIdx.x * 4 + wave;
    if (node >= N) return;
    int s0 = rp[node], end = rp[node + 1];
    float di = dinv[node];
    for (int s = s0 + lane; s < end; s += 64) {
        float2 r = er[s];
        int src = __float_as_int(r.x);
        r.y = dinv[src] * r.y * di;
        er[s] = r;
    }
}

// ---------------- weight prep: transpose + cast to bf16 ----------------
__global__ void prep_w(const float* __restrict__ gcn_W, const float* __restrict__ gat_W,
                       const float* __restrict__ Win, ushort_t* __restrict__ wt,
                       ushort_t* __restrict__ wtin) {
    int idx = blockIdx.x * 256 + threadIdx.x;
    if (idx < 10 * 16384) {
        int l = idx >> 14, r = idx & 16383;
        int n = r >> 7, k = r & 127;
        const float* src = (l < 5) ? (gcn_W + l * 16384) : (gat_W + (l - 5) * 16384);
        wt[idx] = f2b(src[k * 128 + n]);
    } else {
        int idx2 = idx - 10 * 16384;
        if (idx2 < 128 * 320) {
            int n = idx2 / 320, k = idx2 - n * 320;
            wtin[idx2] = f2b(k < 300 ? Win[k * 128 + n] : 0.f);
        }
    }
}

// ---------------- cat projection: cp[400][128] = cat_emb @ Win[300:400] ----------------
__global__ void cat_proj_k(const float* __restrict__ ce, const float* __restrict__ Win,
                           float* __restrict__ cp) {
    __shared__ float row[100];
    int r = blockIdx.x, tid = threadIdx.x;   // 128 threads
    if (tid < 100) row[tid] = ce[r * 100 + tid];
    __syncthreads();
    float acc = 0.f;
    #pragma unroll 4
    for (int k = 0; k < 100; ++k) acc += row[k] * Win[(300 + k) * 128 + tid];
    cp[r * 128 + tid] = acc;
}

// ---------------- poi projection: pp[POI_LEN][128] bf16 = poi_emb @ Win[0:300] (MFMA) ---
__launch_bounds__(256)
__global__ void poi_gemm(const float* __restrict__ pe, const ushort_t* __restrict__ wtin,
                         ushort_t* __restrict__ pp, int P) {
    __shared__ __align__(16) ushort_t As[64 * 328];
    int tid = threadIdx.x;
    int wid = tid >> 6, lane = tid & 63;
    int r0 = blockIdx.x * 64;
    #pragma unroll
    for (int p = 0; p < 80; ++p) {
        int idx = tid + p * 256;
        int row = idx / 320, k = idx - row * 320;
        float v = 0.f;
        if (k < 300 && (r0 + row) < P) v = pe[(size_t)(r0 + row) * 300 + k];
        As[row * 328 + k] = f2b(v);
    }
    __syncthreads();
    int m = lane & 15, q = lane >> 4;
    short8v af[10];
    #pragma unroll
    for (int kc = 0; kc < 10; ++kc)
        af[kc] = *(const short8v*)&As[(wid * 16 + m) * 328 + kc * 32 + q * 8];
    #pragma unroll
    for (int ct = 0; ct < 8; ++ct) {
        const ushort_t* wr = wtin + (size_t)(ct * 16 + m) * 320 + q * 8;
        floatx4 acc = {0.f, 0.f, 0.f, 0.f};
        #pragma unroll
        for (int kc = 0; kc < 10; ++kc) {
            short8v b = *(const short8v*)(wr + kc * 32);
            acc = __builtin_amdgcn_mfma_f32_16x16x32_bf16(af[kc], b, acc, 0, 0, 0);
        }
        int col = ct * 16 + m;
        #pragma unroll
        for (int rg = 0; rg < 4; ++rg) {
            int row = r0 + wid * 16 + q * 4 + rg;
            if (row < P) pp[(size_t)row * 128 + col] = f2b(acc[rg]);
        }
    }
}

// ---------------- layer GEMM (MFMA): xw[N][128] bf16 = x_bf @ W (wt = W^T bf16) --------
__launch_bounds__(256)
__global__ void gemm_mfma(const ushort_t* __restrict__ xb, const ushort_t* __restrict__ wt,
                          ushort_t* __restrict__ xw, int N) {
    __shared__ __align__(16) ushort_t As[64 * 136];
    int tid = threadIdx.x;
    int wid = tid >> 6, lane = tid & 63;
    int r0 = blockIdx.x * 64;
    #pragma unroll
    for (int p = 0; p < 4; ++p) {
        int idx = tid + p * 256;
        int row = idx >> 4, c8 = idx & 15;
        short8v v = *(const short8v*)&xb[(size_t)(r0 + row) * 128 + c8 * 8];
        *(short8v*)&As[row * 136 + c8 * 8] = v;
    }
    __syncthreads();
    int m = lane & 15, q = lane >> 4;
    const int ar = (wid * 16 + m) * 136 + q * 8;
    short8v a0 = *(const short8v*)&As[ar];
    short8v a1 = *(const short8v*)&As[ar + 32];
    short8v a2 = *(const short8v*)&As[ar + 64];
    short8v a3 = *(const short8v*)&As[ar + 96];
    #pragma unroll
    for (int ct = 0; ct < 8; ++ct) {
        const ushort_t* wr = wt + (size_t)(ct * 16 + m) * 128 + q * 8;
        short8v b0 = *(const short8v*)(wr);
        short8v b1 = *(const short8v*)(wr + 32);
        short8v b2 = *(const short8v*)(wr + 64);
        short8v b3 = *(const short8v*)(wr + 96);
        floatx4 acc = {0.f, 0.f, 0.f, 0.f};
        acc = __builtin_amdgcn_mfma_f32_16x16x32_bf16(a0, b0, acc, 0, 0, 0);
        acc = __builtin_amdgcn_mfma_f32_16x16x32_bf16(a1, b1, acc, 0, 0, 0);
        acc = __builtin_amdgcn_mfma_f32_16x16x32_bf16(a2, b2, acc, 0, 0, 0);
        acc = __builtin_amdgcn_mfma_f32_16x16x32_bf16(a3, b3, acc, 0, 0, 0);
        int col = ct * 16 + m;
        #pragma unroll
        for (int rg = 0; rg < 4; ++rg) {
            int row = r0 + wid * 16 + q * 4 + rg;
            if (row < N) xw[(size_t)row * 128 + col] = f2b(acc[rg]);
        }
    }
}

// ---------------- combine: xw0 = pp[poi_id] + cp[cat_id] + feat3 @ Win[400:403] --------
__global__ void combine_k(const ushort_t* __restrict__ pp, const float* __restrict__ cp,
                          const int* __restrict__ poi_ids, const int* __restrict__ cat_ids,
                          const float* __restrict__ feat3, const float* __restrict__ Win,
                          ushort_t* __restrict__ xw, int N) {
    __shared__ float wf0[128], wf1[128], wf2[128];
    int tid = threadIdx.x;
    if (tid < 128) {
        wf0[tid] = Win[400 * 128 + tid];
        wf1[tid] = Win[401 * 128 + tid];
        wf2[tid] = Win[402 * 128 + tid];
    }
    __syncthreads();
    int node = blockIdx.x * 2 + (tid >> 7);
    int c = tid & 127;
    if (node >= N) return;
    int pid = poi_ids[node], cid = cat_ids[node];
    float f0 = feat3[node * 3], f1 = feat3[node * 3 + 1], f2 = feat3[node * 3 + 2];
    float v = b2f(pp[(size_t)pid * 128 + c]) + cp[cid * 128 + c]
            + f0 * wf0[c] + f1 * wf1[c] + f2 * wf2[c];
    xw[(size_t)node * 128 + c] = f2b(v);
}

// ---------------- aggregation ----------------
// one wave per node; lane covers 2 channels; 8 gathers in flight.
// MODE 0: GCN (coef = er.y).  MODE 1: input layer (GCN coef + fused leaky + bf16 copy).
// MODE 2: GAT (softmax over al[src]+ar[node] computed inline; er.y unused).
template <int MODE>
__launch_bounds__(256)
__global__ void agg_k(const ushort_t* __restrict__ xw, const int* __restrict__ rp,
                      const float2* __restrict__ er,
                      const float* __restrict__ al, const float* __restrict__ ar,
                      const float* __restrict__ bias, float* __restrict__ g,
                      ushort_t* __restrict__ xb, int N) {
    int wave = threadIdx.x >> 6, lane = threadIdx.x & 63;
    int node = blockIdx.x * 4 + wave;
    if (node >= N) return;
    int s0 = __builtin_amdgcn_readfirstlane(rp[node]);
    int end = __builtin_amdgcn_readfirstlane(rp[node + 1]);
    float mmax = 0.f, inv = 0.f, ari = 0.f;
    if (MODE == 2) {
        ari = ar[node];
        float mm = -1e30f;
        for (int s = s0 + lane; s < end; s += 64) {
            int src = __float_as_int(er[s].x);
            float e = al[src] + ari; e = e > 0.f ? e : 0.2f * e;
            mm = fmaxf(mm, e);
        }
        #pragma unroll
        for (int off = 32; off; off >>= 1) mm = fmaxf(mm, __shfl_xor(mm, off));
        float ds = 0.f;
        for (int s = s0 + lane; s < end; s += 64) {
            int src = __float_as_int(er[s].x);
            float e = al[src] + ari; e = e > 0.f ? e : 0.2f * e;
            ds += __expf(e - mm);
        }
        #pragma unroll
        for (int off = 32; off; off >>= 1) ds += __shfl_xor(ds, off);
        mmax = mm;
        inv = 1.f / ds;
    }
    int c = lane * 2;
    float ax = 0.f, ay = 0.f;
    int s = s0;
    for (; s + 8 <= end; s += 8) {
        float2 r[8]; ushort2 u[8]; float cf[8];
        #pragma unroll
        for (int j = 0; j < 8; ++j) r[j] = er[s + j];
        #pragma unroll
        for (int j = 0; j < 8; ++j) {
            int src = __float_as_int(r[j].x);
            u[j] = *(const ushort2*)&xw[(size_t)src * 128 + c];
            if (MODE == 2) {
                float e = al[src] + ari; e = e > 0.f ? e : 0.2f * e;
                cf[j] = __expf(e - mmax) * inv;
            } else cf[j] = r[j].y;
        }
        #pragma unroll
        for (int j = 0; j < 8; ++j) {
            ax += cf[j] * b2f(u[j].x);
            ay += cf[j] * b2f(u[j].y);
        }
    }
    for (; s < end; ++s) {
        float2 r = er[s];
        int src = __float_as_int(r.x);
        float cf;
        if (MODE == 2) {
            float e = al[src] + ari; e = e > 0.f ? e : 0.2f * e;
            cf = __expf(e - mmax) * inv;
        } else cf = r.y;
        ushort2 u = *(const ushort2*)&xw[(size_t)src * 128 + c];
        ax += cf * b2f(u.x);
        ay += cf * b2f(u.y);
    }
    float2 b = *(const float2*)&bias[c];
    ax += b.x; ay += b.y;
    if (MODE == 1) {
        ax = leaky01(ax); ay = leaky01(ay);
        float2 o; o.x = ax; o.y = ay;
        *(float2*)&g[(size_t)node * 128 + c] = o;
        ushort2 ub; ub.x = f2b(ax); ub.y = f2b(ay);
        *(ushort2*)&xb[(size_t)node * 128 + c] = ub;
    } else {
        float2 o; o.x = ax; o.y = ay;
        *(float2*)&g[(size_t)node * 128 + c] = o;
    }
}

// ---------------- GraphNorm moments (float4 streaming) ----------------
__global__ void moments_k(const float* __restrict__ g, float* mom, int n32) {
    __shared__ float s1s[256][4], s2s[256][4];
    int tid = threadIdx.x;
    long long T = (long long)gridDim.x * 256;
    float a1[4] = {0.f, 0.f, 0.f, 0.f}, a2[4] = {0.f, 0.f, 0.f, 0.f};
    const float4* g4 = (const float4*)g;
    for (long long idx = (long long)blockIdx.x * 256 + tid; idx < n32; idx += T) {
        float4 v = g4[idx];
        a1[0] += v.x; a2[0] += v.x * v.x;
        a1[1] += v.y; a2[1] += v.y * v.y;
        a1[2] += v.z; a2[2] += v.z * v.z;
        a1[3] += v.w; a2[3] += v.w * v.w;
    }
    #pragma unroll
    for (int j = 0; j < 4; ++j) { s1s[tid][j] = a1[j]; s2s[tid][j] = a2[j]; }
    __syncthreads();
    if (tid < 32) {
        float r1[4] = {0.f, 0.f, 0.f, 0.f}, r2[4] = {0.f, 0.f, 0.f, 0.f};
        for (int t = tid; t < 256; t += 32) {
            #pragma unroll
            for (int j = 0; j < 4; ++j) { r1[j] += s1s[t][j]; r2[j] += s2s[t][j]; }
        }
        #pragma unroll
        for (int j = 0; j < 4; ++j) {
            atomicAdd(&mom[4 * tid + j], r1[j]);
            atomicAdd(&mom[128 + 4 * tid + j], r2[j]);
        }
    }
}

// x += leaky( gamma*rsqrt(var+eps)*(g - alpha*mean) + beta ); also write x_bf (bf16)
__global__ void normresid_k(float* __restrict__ x, const float* __restrict__ g,
                            const float* __restrict__ mom,
                            const float* __restrict__ gamma, const float* __restrict__ beta,
                            const float* __restrict__ alpha, ushort_t* __restrict__ xb,
                            int n32, int N) {
    __shared__ float sc[128], sh[128];
    int tid = threadIdx.x;
    if (tid < 128) {
        float m = mom[tid] / (float)N;
        float a = alpha[tid];
        float var = mom[128 + tid] / (float)N - 2.f * a * m * m + a * a * m * m;
        float s = gamma[tid] * rsqrtf(var + 1e-5f);
        sc[tid] = s;
        sh[tid] = beta[tid] - s * a * m;
    }
    __syncthreads();
    const float4* g4 = (const float4*)g;
    float4* x4 = (float4*)x;
    ushort4* xb4 = (ushort4*)xb;
    for (long long idx = (long long)blockIdx.x * 256 + tid; idx < n32;
         idx += (long long)gridDim.x * 256) {
        int c0 = (int)((idx * 4) & 127);
        float4 gv = g4[idx];
        float4 xv = x4[idx];
        xv.x += leaky01(sc[c0] * gv.x + sh[c0]);
        xv.y += leaky01(sc[c0 + 1] * gv.y + sh[c0 + 1]);
        xv.z += leaky01(sc[c0 + 2] * gv.z + sh[c0 + 2]);
        xv.w += leaky01(sc[c0 + 3] * gv.w + sh[c0 + 3]);
        x4[idx] = xv;
        ushort4 ub;
        ub.x = f2b(xv.x); ub.y = f2b(xv.y); ub.z = f2b(xv.z); ub.w = f2b(xv.w);
        xb4[idx] = ub;
    }
}

// ---------------- GAT al/ar ----------------
__global__ void alar_k(const ushort_t* __restrict__ xw, const float* __restrict__ asrc,
                       const float* __restrict__ adst, float* al, float* ar, int N) {
    __shared__ float ls[128], ld[128];
    int tid = threadIdx.x;
    if (tid < 128) { ls[tid] = asrc[tid]; ld[tid] = adst[tid]; }
    __syncthreads();
    int i = blockIdx.x * 256 + tid;
    if (i >= N) return;
    const ushort_t* row = xw + (size_t)i * 128;
    float a = 0.f, b = 0.f;
    #pragma unroll 4
    for (int c = 0; c < 128; c += 4) {
        ushort4 u = *(const ushort4*)(row + c);
        float f0 = b2f(u.x), f1 = b2f(u.y), f2 = b2f(u.z), f3 = b2f(u.w);
        a += f0 * ls[c] + f1 * ls[c + 1] + f2 * ls[c + 2] + f3 * ls[c + 3];
        b += f0 * ld[c] + f1 * ld[c + 1] + f2 * ld[c + 2] + f3 * ld[c + 3];
    }
    al[i] = a; ar[i] = b;
}

// ---------------- output conv + FC head ----------------
__global__ void ydot_k(const float* __restrict__ x, const float* __restrict__ Wout,
                       float* yv, int N) {
    __shared__ float w[128];
    int tid = threadIdx.x;
    if (tid < 128) w[tid] = Wout[tid];
    __syncthreads();
    int i = blockIdx.x * 256 + tid;
    if (i >= N) return;
    const float* row = x + (size_t)i * 128;
    float acc = 0.f;
    #pragma unroll 4
    for (int c = 0; c < 128; c += 4) {
        float4 v = *(const float4*)(row + c);
        acc += v.x * w[c] + v.y * w[c + 1] + v.z * w[c + 2] + v.w * w[c + 3];
    }
    yv[i] = acc;
}

// wave per node: xs = leaky( sum coef*yv[src] + b_out )
__global__ void aggs_k(const float* __restrict__ yv, const int* __restrict__ rp,
                       const float2* __restrict__ er,
                       const float* __restrict__ b_out, float* xs, int N) {
    int wave = threadIdx.x >> 6, lane = threadIdx.x & 63;
    int node = blockIdx.x * 4 + wave;
    if (node >= N) return;
    int s0 = rp[node], end = rp[node + 1];
    float acc = 0.f;
    for (int s = s0 + lane; s < end; s += 64) {
        float2 r = er[s];
        acc += r.y * yv[__float_as_int(r.x)];
    }
    #pragma unroll
    for (int off = 32; off; off >>= 1) acc += __shfl_xor(acc, off);
    if (lane == 0) xs[node] = leaky01(acc + b_out[0]);
}

__global__ void fc1_k(const float* __restrict__ xs, const float* __restrict__ W1,
                      float* hacc, int N) {
    __shared__ float sd[256];
    int tid = threadIdx.x;
    int j = tid & 127, half = tid >> 7;
    int r0 = blockIdx.x * 256;
    float acc = 0.f;
    for (int rr = half; rr < 256; rr += 2) {
        int r = r0 + rr;
        if (r < N) acc += xs[r] * W1[(size_t)r * 128 + j];
    }
    sd[tid] = acc;
    __syncthreads();
    if (tid < 128) atomicAdd(&hacc[tid], sd[tid] + sd[tid + 128]);
}

__global__ void fc2_k(const float* __restrict__ hacc, const float* __restrict__ b1,
                      const float* __restrict__ W2, const float* __restrict__ b2v,
                      float* out, int P) {
    __shared__ float hs[128];
    int tid = threadIdx.x;
    if (tid < 128) {
        float h = hacc[tid] + b1[tid];
        hs[tid] = h > 0.f ? h : 0.f;
    }
    __syncthreads();
    int p = blockIdx.x * 256 + tid;
    if (p >= P) return;
    float acc = 0.f;
    #pragma unroll 8
    for (int j = 0; j < 128; ++j) acc += hs[j] * W2[(size_t)j * P + p];
    acc += b2v[p];
    out[p] = acc > 0.f ? acc : 0.f;
}

// ---------------- launcher ----------------
extern "C" void kernel_launch(void* const* d_in, const int* in_sizes, int n_in,
                              void* d_out, int out_size, void* d_ws, size_t ws_size,
                              hipStream_t stream) {
    const int*   poi_ids  = (const int*)d_in[0];
    const int*   cat_ids  = (const int*)d_in[1];
    const float* feat3    = (const float*)d_in[2];
    const int*   ei       = (const int*)d_in[3];
    const float* ew       = (const float*)d_in[4];
    const float* poi_emb  = (const float*)d_in[5];
    const float* cat_emb  = (const float*)d_in[6];
    const float* Win      = (const float*)d_in[7];
    const float* b_in     = (const float*)d_in[8];
    const float* gcn_W    = (const float*)d_in[9];
    const float* gcn_b    = (const float*)d_in[10];
    const float* gn_gamma = (const float*)d_in[11];
    const float* gn_beta  = (const float*)d_in[12];
    const float* gn_alpha = (const float*)d_in[13];
    const float* gat_W    = (const float*)d_in[14];
    const float* gat_asrc = (const float*)d_in[15];
    const float* gat_adst = (const float*)d_in[16];
    const float* gat_b    = (const float*)d_in[17];
    const float* Wout     = (const float*)d_in[18];
    const float* b_out    = (const float*)d_in[19];
    const float* fc_W1    = (const float*)d_in[20];
    const float* fc_b1    = (const float*)d_in[21];
    const float* fc_W2    = (const float*)d_in[22];
    const float* fc_b2    = (const float*)d_in[23];

    const int N = in_sizes[0];
    const int E = in_sizes[4];
    const int POI = in_sizes[5] / 300;
    const int P = out_size;
    const int TOT = E + N;
    const int n128 = N * 128;
    const int n32 = n128 / 4;
    const int NPAD = ((N + 63) / 64) * 64;
    const int PPAD = ((POI + 63) / 64) * 64;

    // workspace carve (256B aligned)
    char* w = (char*)d_ws;
    size_t off = 0;
    auto take = [&](size_t bytes) -> char* {
        char* p = w + off;
        off = (off + bytes + 255) & ~(size_t)255;
        return p;
    };
    float*    x    = (float*)take((size_t)n128 * 4);
    float*    g    = (float*)take((size_t)n128 * 4);
    ushort_t* xb   = (ushort_t*)take((size_t)NPAD * 128 * 2);
    ushort_t* xw   = (ushort_t*)take((size_t)NPAD * 128 * 2);
    ushort_t* pp   = (ushort_t*)take((size_t)PPAD * 128 * 2);
    float*    cp   = (float*)take((size_t)400 * 128 * 4);
    ushort_t* wt   = (ushort_t*)take((size_t)10 * 16384 * 2);
    ushort_t* wtin = (ushort_t*)take((size_t)128 * 320 * 2);
    int*    rp   = (int*)take((size_t)(N + 1) * 4);
    int*    cnt  = (int*)take((size_t)N * 4);
    int*    fill = (int*)take((size_t)N * 4);
    float*  dinv = (float*)take((size_t)N * 4);
    float2* er   = (float2*)take((size_t)TOT * 8);
    float*  al   = (float*)take((size_t)N * 4);
    float*  ar   = (float*)take((size_t)N * 4);
    float*  yv   = (float*)take((size_t)N * 4);
    float*  xs   = (float*)take((size_t)N * 4);
    float*  mom  = (float*)take((size_t)(10 * 256 + 128) * 4);
    float*  hacc = mom + 10 * 256;

    const int gN    = (N + 255) / 256;
    const int gE    = (E + 255) / 256;
    const int gMM   = NPAD / 64;
    const int gPOI  = PPAD / 64;
    const int gW    = (N + 3) / 4;    // wave-per-node grids
    const int gP    = (P + 255) / 256;

    hipMemsetAsync(mom, 0, (size_t)(10 * 256 + 128) * 4, stream);

    // CSR build
    init_k<<<gN, 256, 0, stream>>>(cnt, N);
    count_k<<<gE, 256, 0, stream>>>(ei, cnt, E);
    scan_k<<<1, 1024, 0, stream>>>(cnt, rp, N);
    post_k<<<gN, 256, 0, stream>>>(rp, fill, er, N);
    scat_k<<<gE, 256, 0, stream>>>(ei, ew, fill, er, E);
    deg_k<<<gW, 256, 0, stream>>>(rp, er, dinv, N);
    coef_k<<<gW, 256, 0, stream>>>(rp, er, dinv, N);

    // weight prep + input conv
    prep_w<<<(10 * 16384 + 128 * 320 + 255) / 256, 256, 0, stream>>>(gcn_W, gat_W, Win, wt, wtin);
    cat_proj_k<<<400, 128, 0, stream>>>(cat_emb, Win, cp);
    poi_gemm<<<gPOI, 256, 0, stream>>>(poi_emb, wtin, pp, POI);
    combine_k<<<(N + 1) / 2, 256, 0, stream>>>(pp, cp, poi_ids, cat_ids, feat3, Win, xw, N);
    agg_k<1><<<gW, 256, 0, stream>>>(xw, rp, er, nullptr, nullptr, b_in, x, xb, N);

    // 5 GcnUnits
    for (int l = 0; l < 5; ++l) {
        // GCN half
        gemm_mfma<<<gMM, 256, 0, stream>>>(xb, wt + (size_t)l * 16384, xw, N);
        agg_k<0><<<gW, 256, 0, stream>>>(xw, rp, er, nullptr, nullptr, gcn_b + l * 128, g, nullptr, N);
        moments_k<<<240, 256, 0, stream>>>(g, mom + (2 * l) * 256, n32);
        normresid_k<<<1024, 256, 0, stream>>>(x, g, mom + (2 * l) * 256,
                                              gn_gamma + l * 128, gn_beta + l * 128,
                                              gn_alpha + l * 128, xb, n32, N);
        // GAT half (attention fused into aggregation)
        gemm_mfma<<<gMM, 256, 0, stream>>>(xb, wt + (size_t)(5 + l) * 16384, xw, N);
        alar_k<<<gN, 256, 0, stream>>>(xw, gat_asrc + l * 128, gat_adst + l * 128, al, ar, N);
        agg_k<2><<<gW, 256, 0, stream>>>(xw, rp, er, al, ar, gat_b + l * 128, g, nullptr, N);
        moments_k<<<240, 256, 0, stream>>>(g, mom + (2 * l + 1) * 256, n32);
        normresid_k<<<1024, 256, 0, stream>>>(x, g, mom + (2 * l + 1) * 256,
                                              gn_gamma + l * 128, gn_beta + l * 128,
                                              gn_alpha + l * 128, xb, n32, N);
    }

    // output conv (C -> 1) + leaky
    ydot_k<<<gN, 256, 0, stream>>>(x, Wout, yv, N);
    aggs_k<<<gW, 256, 0, stream>>>(yv, rp, er, b_out, xs, N);

    // FC head
    fc1_k<<<(N + 255) / 256, 256, 0, stream>>>(xs, fc_W1, hacc, N);
    fc2_k<<<gP, 256, 0, stream>>>(hacc, fc_b1, fc_W2, fc_b2, (float*)d_out, P);
}

// Round 6
// 1453.892 us; speedup vs baseline: 2.6014x; 1.0873x over previous
//
#include <hip/hip_runtime.h>

typedef unsigned short ushort_t;
typedef __attribute__((ext_vector_type(8))) short short8v;
typedef __attribute__((ext_vector_type(4))) float floatx4;

__device__ __forceinline__ float b2f(ushort_t u) {
    unsigned int x = ((unsigned int)u) << 16;
    float f; __builtin_memcpy(&f, &x, 4); return f;
}
__device__ __forceinline__ ushort_t f2b(float f) {
    unsigned int x; __builtin_memcpy(&x, &f, 4);
    unsigned int lsb = (x >> 16) & 1u;
    x += 0x7fffu + lsb;
    return (ushort_t)(x >> 16);
}
__device__ __forceinline__ float leaky01(float v) { return v > 0.f ? v : 0.01f * v; }

// ---------------- CSR build ----------------
__global__ void init_k(int* cnt, int N) {
    int i = blockIdx.x * 256 + threadIdx.x;
    if (i < N) cnt[i] = 1;   // self-loop
}

// count + record intra-segment position (>=1; slot 0 = self-loop)
__global__ void count_k(const int* __restrict__ ei, int* cnt, int* pos, int E) {
    int e = blockIdx.x * 256 + threadIdx.x;
    if (e < E) pos[e] = atomicAdd(&cnt[ei[E + e]], 1);
}

__launch_bounds__(1024)
__global__ void scan_k(const int* __restrict__ cnt, int* rp, int n) {
    __shared__ int wsum[16];
    int tid = threadIdx.x; int lane = tid & 63, wid = tid >> 6;
    int base = 0;
    for (int start = 0; start < n; start += 4096) {
        int v[4]; int s = 0;
        #pragma unroll
        for (int j = 0; j < 4; ++j) {
            int i = start + tid * 4 + j;
            v[j] = (i < n) ? cnt[i] : 0; s += v[j];
        }
        int sc = s;
        #pragma unroll
        for (int off = 1; off < 64; off <<= 1) {
            int t = __shfl_up(sc, off);
            if (lane >= off) sc += t;
        }
        if (lane == 63) wsum[wid] = sc;
        __syncthreads();
        if (wid == 0) {
            int ws = (lane < 16) ? wsum[lane] : 0;
            #pragma unroll
            for (int off = 1; off < 16; off <<= 1) {
                int t = __shfl_up(ws, off);
                if (lane >= off) ws += t;
            }
            if (lane < 16) wsum[lane] = ws;
        }
        __syncthreads();
        int wbase = (wid > 0) ? wsum[wid - 1] : 0;
        int excl = base + wbase + (sc - s);
        #pragma unroll
        for (int j = 0; j < 4; ++j) {
            int i = start + tid * 4 + j;
            if (i < n) rp[i] = excl;
            excl += v[j];
        }
        int total = wsum[15];
        __syncthreads();
        base += total;
    }
    if (tid == 0) rp[n] = base;
}

// self-loop record at segment start
__global__ void post_k(const int* __restrict__ rp, float2* er, int N) {
    int i = blockIdx.x * 256 + threadIdx.x;
    if (i < N) er[rp[i]] = make_float2(__int_as_float(i), 1.0f);
}

__global__ void scat_k(const int* __restrict__ ei, const float* __restrict__ ew,
                       const int* __restrict__ rp, const int* __restrict__ pos,
                       float2* er, int E) {
    int e = blockIdx.x * 256 + threadIdx.x;
    if (e < E) {
        int dst = ei[E + e];
        er[rp[dst] + pos[e]] = make_float2(__int_as_float(ei[e]), ew[e]);
    }
}

// wave per node: dinv[i] = rsqrt(sum of segment weights)
__global__ void deg_k(const int* __restrict__ rp, const float2* __restrict__ er,
                      float* dinv, int N) {
    int wave = threadIdx.x >> 6, lane = threadIdx.x & 63;
    int node = blockIdx.x * 4 + wave;
    if (node >= N) return;
    int s0 = rp[node], end = rp[node + 1];
    float sum = 0.f;
    for (int s = s0 + lane; s < end; s += 64) sum += er[s].y;
    #pragma unroll
    for (int off = 32; off; off >>= 1) sum += __shfl_xor(sum, off);
    if (lane == 0) dinv[node] = rsqrtf(sum);
}

// ---------------- weight prep: transpose + cast to bf16 ----------------
__global__ void prep_w(const float* __restrict__ gcn_W, const float* __restrict__ gat_W,
                       const float* __restrict__ Win, ushort_t* __restrict__ wt,
                       ushort_t* __restrict__ wtin) {
    int idx = blockIdx.x * 256 + threadIdx.x;
    if (idx < 10 * 16384) {
        int l = idx >> 14, r = idx & 16383;
        int n = r >> 7, k = r & 127;
        const float* src = (l < 5) ? (gcn_W + l * 16384) : (gat_W + (l - 5) * 16384);
        wt[idx] = f2b(src[k * 128 + n]);
    } else {
        int idx2 = idx - 10 * 16384;
        if (idx2 < 128 * 320) {
            int n = idx2 / 320, k = idx2 - n * 320;
            wtin[idx2] = f2b(k < 300 ? Win[k * 128 + n] : 0.f);
        }
    }
}

// ---------------- cat projection: cp[400][128] = cat_emb @ Win[300:400] ----------------
__global__ void cat_proj_k(const float* __restrict__ ce, const float* __restrict__ Win,
                           float* __restrict__ cp) {
    __shared__ float row[100];
    int r = blockIdx.x, tid = threadIdx.x;   // 128 threads
    if (tid < 100) row[tid] = ce[r * 100 + tid];
    __syncthreads();
    float acc = 0.f;
    #pragma unroll 4
    for (int k = 0; k < 100; ++k) acc += row[k] * Win[(300 + k) * 128 + tid];
    cp[r * 128 + tid] = acc;
}

// ---------------- poi projection: pp[POI_LEN][128] bf16 = poi_emb @ Win[0:300] (MFMA) ---
__launch_bounds__(256)
__global__ void poi_gemm(const float* __restrict__ pe, const ushort_t* __restrict__ wtin,
                         ushort_t* __restrict__ pp, int P) {
    __shared__ __align__(16) ushort_t As[64 * 328];
    int tid = threadIdx.x;
    int wid = tid >> 6, lane = tid & 63;
    int r0 = blockIdx.x * 64;
    #pragma unroll
    for (int p = 0; p < 80; ++p) {
        int idx = tid + p * 256;
        int row = idx / 320, k = idx - row * 320;
        float v = 0.f;
        if (k < 300 && (r0 + row) < P) v = pe[(size_t)(r0 + row) * 300 + k];
        As[row * 328 + k] = f2b(v);
    }
    __syncthreads();
    int m = lane & 15, q = lane >> 4;
    short8v af[10];
    #pragma unroll
    for (int kc = 0; kc < 10; ++kc)
        af[kc] = *(const short8v*)&As[(wid * 16 + m) * 328 + kc * 32 + q * 8];
    #pragma unroll
    for (int ct = 0; ct < 8; ++ct) {
        const ushort_t* wr = wtin + (size_t)(ct * 16 + m) * 320 + q * 8;
        floatx4 acc = {0.f, 0.f, 0.f, 0.f};
        #pragma unroll
        for (int kc = 0; kc < 10; ++kc) {
            short8v b = *(const short8v*)(wr + kc * 32);
            acc = __builtin_amdgcn_mfma_f32_16x16x32_bf16(af[kc], b, acc, 0, 0, 0);
        }
        int col = ct * 16 + m;
        #pragma unroll
        for (int rg = 0; rg < 4; ++rg) {
            int row = r0 + wid * 16 + q * 4 + rg;
            if (row < P) pp[(size_t)row * 128 + col] = f2b(acc[rg]);
        }
    }
}

// ---------------- fused layer GEMM (MFMA) ----------------
// NORM: while staging, x += leaky(graphnorm(g)) (in place), A = bf16(x_new)
// ALAR: epilogue computes al/ar = xw_row . asrc/adst (fp32 accs)
template <int NORM, int ALAR>
__launch_bounds__(256)
__global__ void gemm_fused(float* __restrict__ x, const float* __restrict__ gsrc,
                           const float* __restrict__ mom,
                           const float* __restrict__ gamma, const float* __restrict__ beta,
                           const float* __restrict__ alpha,
                           const ushort_t* __restrict__ wt,
                           const float* __restrict__ asrc, const float* __restrict__ adst,
                           ushort_t* __restrict__ xw,
                           float* __restrict__ al, float* __restrict__ ar, int N) {
    __shared__ __align__(16) ushort_t As[64 * 136];
    __shared__ float sc[128], sh[128];
    int tid = threadIdx.x;
    if (NORM) {
        if (tid < 128) {
            float mmean = mom[tid] / (float)N;
            float a = alpha[tid];
            float var = mom[128 + tid] / (float)N - 2.f * a * mmean * mmean + a * a * mmean * mmean;
            float s = gamma[tid] * rsqrtf(var + 1e-5f);
            sc[tid] = s;
            sh[tid] = beta[tid] - s * a * mmean;
        }
        __syncthreads();
    }
    int r0 = blockIdx.x * 64;
    #pragma unroll
    for (int p = 0; p < 8; ++p) {
        int idx = tid + p * 256;          // 0..2047 float4 chunks
        int row = idx >> 5, c4 = (idx & 31) * 4;
        int grow = r0 + row;
        float4 xv = make_float4(0.f, 0.f, 0.f, 0.f);
        if (grow < N) {
            xv = *(const float4*)&x[(size_t)grow * 128 + c4];
            if (NORM) {
                float4 gv = *(const float4*)&gsrc[(size_t)grow * 128 + c4];
                xv.x += leaky01(sc[c4] * gv.x + sh[c4]);
                xv.y += leaky01(sc[c4 + 1] * gv.y + sh[c4 + 1]);
                xv.z += leaky01(sc[c4 + 2] * gv.z + sh[c4 + 2]);
                xv.w += leaky01(sc[c4 + 3] * gv.w + sh[c4 + 3]);
                *(float4*)&x[(size_t)grow * 128 + c4] = xv;
            }
        }
        ushort4 b;
        b.x = f2b(xv.x); b.y = f2b(xv.y); b.z = f2b(xv.z); b.w = f2b(xv.w);
        *(ushort4*)&As[row * 136 + c4] = b;
    }
    __syncthreads();
    int wid = tid >> 6, lane = tid & 63;
    int m = lane & 15, q = lane >> 4;
    const int arr = (wid * 16 + m) * 136 + q * 8;
    short8v a0 = *(const short8v*)&As[arr];
    short8v a1 = *(const short8v*)&As[arr + 32];
    short8v a2 = *(const short8v*)&As[arr + 64];
    short8v a3 = *(const short8v*)&As[arr + 96];
    float alsum[4] = {0.f, 0.f, 0.f, 0.f}, arsum[4] = {0.f, 0.f, 0.f, 0.f};
    #pragma unroll
    for (int ct = 0; ct < 8; ++ct) {
        const ushort_t* wr = wt + (size_t)(ct * 16 + m) * 128 + q * 8;
        short8v b0 = *(const short8v*)(wr);
        short8v b1 = *(const short8v*)(wr + 32);
        short8v b2 = *(const short8v*)(wr + 64);
        short8v b3 = *(const short8v*)(wr + 96);
        floatx4 acc = {0.f, 0.f, 0.f, 0.f};
        acc = __builtin_amdgcn_mfma_f32_16x16x32_bf16(a0, b0, acc, 0, 0, 0);
        acc = __builtin_amdgcn_mfma_f32_16x16x32_bf16(a1, b1, acc, 0, 0, 0);
        acc = __builtin_amdgcn_mfma_f32_16x16x32_bf16(a2, b2, acc, 0, 0, 0);
        acc = __builtin_amdgcn_mfma_f32_16x16x32_bf16(a3, b3, acc, 0, 0, 0);
        int col = ct * 16 + m;
        if (ALAR) {
            float av = asrc[col], dv = adst[col];
            #pragma unroll
            for (int rg = 0; rg < 4; ++rg) {
                alsum[rg] += acc[rg] * av;
                arsum[rg] += acc[rg] * dv;
            }
        }
        #pragma unroll
        for (int rg = 0; rg < 4; ++rg) {
            int row = r0 + wid * 16 + q * 4 + rg;
            if (row < N) xw[(size_t)row * 128 + col] = f2b(acc[rg]);
        }
    }
    if (ALAR) {
        #pragma unroll
        for (int rg = 0; rg < 4; ++rg) {
            #pragma unroll
            for (int off = 1; off < 16; off <<= 1) {
                alsum[rg] += __shfl_xor(alsum[rg], off);
                arsum[rg] += __shfl_xor(arsum[rg], off);
            }
        }
        if (m == 0) {
            #pragma unroll
            for (int rg = 0; rg < 4; ++rg) {
                int row = r0 + wid * 16 + q * 4 + rg;
                if (row < N) { al[row] = alsum[rg]; ar[row] = arsum[rg]; }
            }
        }
    }
}

// ---------------- combine: xw0 = pp[poi_id] + cp[cat_id] + feat3 @ Win[400:403] --------
__global__ void combine_k(const ushort_t* __restrict__ pp, const float* __restrict__ cp,
                          const int* __restrict__ poi_ids, const int* __restrict__ cat_ids,
                          const float* __restrict__ feat3, const float* __restrict__ Win,
                          ushort_t* __restrict__ xw, int N) {
    __shared__ float wf0[128], wf1[128], wf2[128];
    int tid = threadIdx.x;
    if (tid < 128) {
        wf0[tid] = Win[400 * 128 + tid];
        wf1[tid] = Win[401 * 128 + tid];
        wf2[tid] = Win[402 * 128 + tid];
    }
    __syncthreads();
    int node = blockIdx.x * 2 + (tid >> 7);
    int c = tid & 127;
    if (node >= N) return;
    int pid = poi_ids[node], cid = cat_ids[node];
    float f0 = feat3[node * 3], f1 = feat3[node * 3 + 1], f2 = feat3[node * 3 + 2];
    float v = b2f(pp[(size_t)pid * 128 + c]) + cp[cid * 128 + c]
            + f0 * wf0[c] + f1 * wf1[c] + f2 * wf2[c];
    xw[(size_t)node * 128 + c] = f2b(v);
}

// ---------------- aggregation ----------------
// one wave per node; lane covers 8 channels (16B), 4 edges/step, unrolled x4
// -> 16 independent 256B row-gathers in flight.
// MODE 0: GCN (coef = dinv[src]*w*dinv[node]).  MODE 1: + fused leaky (input layer).
// MODE 2: GAT softmax over al[src]+ar[node], computed inline.
template <int MODE>
__launch_bounds__(256)
__global__ void agg_k(const ushort_t* __restrict__ xw, const int* __restrict__ rp,
                      const float2* __restrict__ er, const float* __restrict__ dinv,
                      const float* __restrict__ al, const float* __restrict__ ar,
                      const float* __restrict__ bias, float* __restrict__ g, int N) {
    int wave = threadIdx.x >> 6, lane = threadIdx.x & 63;
    int node = blockIdx.x * 4 + wave;
    if (node >= N) return;
    int s0 = __builtin_amdgcn_readfirstlane(rp[node]);
    int end = __builtin_amdgcn_readfirstlane(rp[node + 1]);
    int g8 = lane >> 4;          // edge subslot 0..3
    int c8 = (lane & 15) * 8;    // channel base
    float dn = 0.f, mmax = 0.f, inv = 0.f, ari = 0.f;
    if (MODE == 2) {
        ari = ar[node];
        float mm = -1e30f;
        for (int s = s0 + lane; s < end; s += 64) {
            int src = __float_as_int(er[s].x);
            float e = al[src] + ari; e = e > 0.f ? e : 0.2f * e;
            mm = fmaxf(mm, e);
        }
        #pragma unroll
        for (int off = 32; off; off >>= 1) mm = fmaxf(mm, __shfl_xor(mm, off));
        float ds = 0.f;
        for (int s = s0 + lane; s < end; s += 64) {
            int src = __float_as_int(er[s].x);
            float e = al[src] + ari; e = e > 0.f ? e : 0.2f * e;
            ds += __expf(e - mm);
        }
        #pragma unroll
        for (int off = 32; off; off >>= 1) ds += __shfl_xor(ds, off);
        mmax = mm;
        inv = 1.f / ds;
    } else {
        dn = dinv[node];
    }
    float acc[8] = {0.f, 0.f, 0.f, 0.f, 0.f, 0.f, 0.f, 0.f};
    auto body = [&](int e) {
        float2 r = er[e];
        int src = __float_as_int(r.x);
        float cf;
        if (MODE == 2) {
            float ev = al[src] + ari; ev = ev > 0.f ? ev : 0.2f * ev;
            cf = __expf(ev - mmax) * inv;
        } else {
            cf = dinv[src] * r.y * dn;
        }
        const short8v u = *(const short8v*)&xw[(size_t)src * 128 + c8];
        #pragma unroll
        for (int k = 0; k < 8; ++k) acc[k] += cf * b2f((ushort_t)u[k]);
    };
    int e = s0 + g8;
    for (; e + 12 < end; e += 16) { body(e); body(e + 4); body(e + 8); body(e + 12); }
    for (; e < end; e += 4) body(e);
    #pragma unroll
    for (int k = 0; k < 8; ++k) {
        acc[k] += __shfl_xor(acc[k], 16);
        acc[k] += __shfl_xor(acc[k], 32);
    }
    if (g8 == 0) {
        float4 o1, o2;
        o1.x = acc[0] + bias[c8];     o1.y = acc[1] + bias[c8 + 1];
        o1.z = acc[2] + bias[c8 + 2]; o1.w = acc[3] + bias[c8 + 3];
        o2.x = acc[4] + bias[c8 + 4]; o2.y = acc[5] + bias[c8 + 5];
        o2.z = acc[6] + bias[c8 + 6]; o2.w = acc[7] + bias[c8 + 7];
        if (MODE == 1) {
            o1.x = leaky01(o1.x); o1.y = leaky01(o1.y); o1.z = leaky01(o1.z); o1.w = leaky01(o1.w);
            o2.x = leaky01(o2.x); o2.y = leaky01(o2.y); o2.z = leaky01(o2.z); o2.w = leaky01(o2.w);
        }
        *(float4*)&g[(size_t)node * 128 + c8] = o1;
        *(float4*)&g[(size_t)node * 128 + c8 + 4] = o2;
    }
}

// ---------------- GraphNorm moments (float4 streaming) ----------------
__global__ void moments_k(const float* __restrict__ g, float* mom, int n32) {
    __shared__ float s1s[256][4], s2s[256][4];
    int tid = threadIdx.x;
    long long T = (long long)gridDim.x * 256;
    float a1[4] = {0.f, 0.f, 0.f, 0.f}, a2[4] = {0.f, 0.f, 0.f, 0.f};
    const float4* g4 = (const float4*)g;
    for (long long idx = (long long)blockIdx.x * 256 + tid; idx < n32; idx += T) {
        float4 v = g4[idx];
        a1[0] += v.x; a2[0] += v.x * v.x;
        a1[1] += v.y; a2[1] += v.y * v.y;
        a1[2] += v.z; a2[2] += v.z * v.z;
        a1[3] += v.w; a2[3] += v.w * v.w;
    }
    #pragma unroll
    for (int j = 0; j < 4; ++j) { s1s[tid][j] = a1[j]; s2s[tid][j] = a2[j]; }
    __syncthreads();
    if (tid < 32) {
        float r1[4] = {0.f, 0.f, 0.f, 0.f}, r2[4] = {0.f, 0.f, 0.f, 0.f};
        for (int t = tid; t < 256; t += 32) {
            #pragma unroll
            for (int j = 0; j < 4; ++j) { r1[j] += s1s[t][j]; r2[j] += s2s[t][j]; }
        }
        #pragma unroll
        for (int j = 0; j < 4; ++j) {
            atomicAdd(&mom[4 * tid + j], r1[j]);
            atomicAdd(&mom[128 + 4 * tid + j], r2[j]);
        }
    }
}

// ---------------- final: x-update (not stored) + dot with Wout ----------------
__global__ void norm_ydot_k(const float* __restrict__ x, const float* __restrict__ g,
                            const float* __restrict__ mom,
                            const float* __restrict__ gamma, const float* __restrict__ beta,
                            const float* __restrict__ alpha, const float* __restrict__ Wout,
                            float* __restrict__ yv, int N) {
    __shared__ float sc[128], sh[128], wv[128];
    int tid = threadIdx.x;
    if (tid < 128) {
        float m = mom[tid] / (float)N;
        float a = alpha[tid];
        float var = mom[128 + tid] / (float)N - 2.f * a * m * m + a * a * m * m;
        float s = gamma[tid] * rsqrtf(var + 1e-5f);
        sc[tid] = s;
        sh[tid] = beta[tid] - s * a * m;
        wv[tid] = Wout[tid];
    }
    __syncthreads();
    int wave = tid >> 6, lane = tid & 63;
    int node = blockIdx.x * 4 + wave;
    if (node >= N) return;
    int c = lane * 2;
    float2 gv = *(const float2*)&g[(size_t)node * 128 + c];
    float2 xv = *(const float2*)&x[(size_t)node * 128 + c];
    float v0 = xv.x + leaky01(sc[c] * gv.x + sh[c]);
    float v1 = xv.y + leaky01(sc[c + 1] * gv.y + sh[c + 1]);
    float acc = v0 * wv[c] + v1 * wv[c + 1];
    #pragma unroll
    for (int off = 32; off; off >>= 1) acc += __shfl_xor(acc, off);
    if (lane == 0) yv[node] = acc;
}

// wave per node: xs = leaky( sum coef*yv[src] + b_out ), coef on the fly
__global__ void aggs_k(const float* __restrict__ yv, const int* __restrict__ rp,
                       const float2* __restrict__ er, const float* __restrict__ dinv,
                       const float* __restrict__ b_out, float* xs, int N) {
    int wave = threadIdx.x >> 6, lane = threadIdx.x & 63;
    int node = blockIdx.x * 4 + wave;
    if (node >= N) return;
    int s0 = rp[node], end = rp[node + 1];
    float dn = dinv[node];
    float acc = 0.f;
    for (int s = s0 + lane; s < end; s += 64) {
        float2 r = er[s];
        int src = __float_as_int(r.x);
        acc += dinv[src] * r.y * dn * yv[src];
    }
    #pragma unroll
    for (int off = 32; off; off >>= 1) acc += __shfl_xor(acc, off);
    if (lane == 0) xs[node] = leaky01(acc + b_out[0]);
}

__global__ void fc1_k(const float* __restrict__ xs, const float* __restrict__ W1,
                      float* hacc, int N) {
    __shared__ float sd[256];
    int tid = threadIdx.x;
    int j = tid & 127, half = tid >> 7;
    int r0 = blockIdx.x * 256;
    float acc = 0.f;
    for (int rr = half; rr < 256; rr += 2) {
        int r = r0 + rr;
        if (r < N) acc += xs[r] * W1[(size_t)r * 128 + j];
    }
    sd[tid] = acc;
    __syncthreads();
    if (tid < 128) atomicAdd(&hacc[tid], sd[tid] + sd[tid + 128]);
}

__global__ void fc2_k(const float* __restrict__ hacc, const float* __restrict__ b1,
                      const float* __restrict__ W2, const float* __restrict__ b2v,
                      float* out, int P) {
    __shared__ float hs[128];
    int tid = threadIdx.x;
    if (tid < 128) {
        float h = hacc[tid] + b1[tid];
        hs[tid] = h > 0.f ? h : 0.f;
    }
    __syncthreads();
    int p = blockIdx.x * 256 + tid;
    if (p >= P) return;
    float acc = 0.f;
    #pragma unroll 8
    for (int j = 0; j < 128; ++j) acc += hs[j] * W2[(size_t)j * P + p];
    acc += b2v[p];
    out[p] = acc > 0.f ? acc : 0.f;
}

// ---------------- launcher ----------------
extern "C" void kernel_launch(void* const* d_in, const int* in_sizes, int n_in,
                              void* d_out, int out_size, void* d_ws, size_t ws_size,
                              hipStream_t stream) {
    const int*   poi_ids  = (const int*)d_in[0];
    const int*   cat_ids  = (const int*)d_in[1];
    const float* feat3    = (const float*)d_in[2];
    const int*   ei       = (const int*)d_in[3];
    const float* ew       = (const float*)d_in[4];
    const float* poi_emb  = (const float*)d_in[5];
    const float* cat_emb  = (const float*)d_in[6];
    const float* Win      = (const float*)d_in[7];
    const float* b_in     = (const float*)d_in[8];
    const float* gcn_W    = (const float*)d_in[9];
    const float* gcn_b    = (const float*)d_in[10];
    const float* gn_gamma = (const float*)d_in[11];
    const float* gn_beta  = (const float*)d_in[12];
    const float* gn_alpha = (const float*)d_in[13];
    const float* gat_W    = (const float*)d_in[14];
    const float* gat_asrc = (const float*)d_in[15];
    const float* gat_adst = (const float*)d_in[16];
    const float* gat_b    = (const float*)d_in[17];
    const float* Wout     = (const float*)d_in[18];
    const float* b_out    = (const float*)d_in[19];
    const float* fc_W1    = (const float*)d_in[20];
    const float* fc_b1    = (const float*)d_in[21];
    const float* fc_W2    = (const float*)d_in[22];
    const float* fc_b2    = (const float*)d_in[23];

    const int N = in_sizes[0];
    const int E = in_sizes[4];
    const int POI = in_sizes[5] / 300;
    const int P = out_size;
    const int TOT = E + N;
    const int n128 = N * 128;
    const int n32 = n128 / 4;
    const int NPAD = ((N + 63) / 64) * 64;
    const int PPAD = ((POI + 63) / 64) * 64;

    // workspace carve (256B aligned)
    char* w = (char*)d_ws;
    size_t off = 0;
    auto take = [&](size_t bytes) -> char* {
        char* p = w + off;
        off = (off + bytes + 255) & ~(size_t)255;
        return p;
    };
    float*    x    = (float*)take((size_t)n128 * 4);
    float*    g    = (float*)take((size_t)n128 * 4);
    ushort_t* xw   = (ushort_t*)take((size_t)NPAD * 128 * 2);
    ushort_t* pp   = (ushort_t*)take((size_t)PPAD * 128 * 2);
    float*    cp   = (float*)take((size_t)400 * 128 * 4);
    ushort_t* wt   = (ushort_t*)take((size_t)10 * 16384 * 2);
    ushort_t* wtin = (ushort_t*)take((size_t)128 * 320 * 2);
    int*    rp   = (int*)take((size_t)(N + 1) * 4);
    int*    cnt  = (int*)take((size_t)N * 4);
    int*    pos  = (int*)take((size_t)E * 4);
    float*  dinv = (float*)take((size_t)N * 4);
    float2* er   = (float2*)take((size_t)TOT * 8);
    float*  al   = (float*)take((size_t)N * 4);
    float*  ar   = (float*)take((size_t)N * 4);
    float*  yv   = (float*)take((size_t)N * 4);
    float*  xs   = (float*)take((size_t)N * 4);
    float*  mom  = (float*)take((size_t)(10 * 256 + 128) * 4);
    float*  hacc = mom + 10 * 256;

    const int gN   = (N + 255) / 256;
    const int gE   = (E + 255) / 256;
    const int gMM  = NPAD / 64;
    const int gPOI = PPAD / 64;
    const int gW   = (N + 3) / 4;
    const int gP   = (P + 255) / 256;

    hipMemsetAsync(mom, 0, (size_t)(10 * 256 + 128) * 4, stream);

    // CSR build
    init_k<<<gN, 256, 0, stream>>>(cnt, N);
    count_k<<<gE, 256, 0, stream>>>(ei, cnt, pos, E);
    scan_k<<<1, 1024, 0, stream>>>(cnt, rp, N);
    post_k<<<gN, 256, 0, stream>>>(rp, er, N);
    scat_k<<<gE, 256, 0, stream>>>(ei, ew, rp, pos, er, E);
    deg_k<<<gW, 256, 0, stream>>>(rp, er, dinv, N);

    // weight prep + input conv
    prep_w<<<(10 * 16384 + 128 * 320 + 255) / 256, 256, 0, stream>>>(gcn_W, gat_W, Win, wt, wtin);
    cat_proj_k<<<400, 128, 0, stream>>>(cat_emb, Win, cp);
    poi_gemm<<<gPOI, 256, 0, stream>>>(poi_emb, wtin, pp, POI);
    combine_k<<<(N + 1) / 2, 256, 0, stream>>>(pp, cp, poi_ids, cat_ids, feat3, Win, xw, N);
    agg_k<1><<<gW, 256, 0, stream>>>(xw, rp, er, dinv, nullptr, nullptr, b_in, x, N);

    // 5 GcnUnits
    for (int l = 0; l < 5; ++l) {
        // GCN half: gemm (fused norm of previous GAT half for l>=1)
        if (l == 0)
            gemm_fused<0, 0><<<gMM, 256, 0, stream>>>(x, nullptr, nullptr, nullptr, nullptr,
                                                      nullptr, wt, nullptr, nullptr,
                                                      xw, nullptr, nullptr, N);
        else
            gemm_fused<1, 0><<<gMM, 256, 0, stream>>>(x, g, mom + (2 * l - 1) * 256,
                                                      gn_gamma + (l - 1) * 128,
                                                      gn_beta + (l - 1) * 128,
                                                      gn_alpha + (l - 1) * 128,
                                                      wt + (size_t)l * 16384, nullptr, nullptr,
                                                      xw, nullptr, nullptr, N);
        agg_k<0><<<gW, 256, 0, stream>>>(xw, rp, er, dinv, nullptr, nullptr,
                                         gcn_b + l * 128, g, N);
        moments_k<<<240, 256, 0, stream>>>(g, mom + (2 * l) * 256, n32);

        // GAT half: gemm with fused norm (this unit's GCN) + alar epilogue
        gemm_fused<1, 1><<<gMM, 256, 0, stream>>>(x, g, mom + (2 * l) * 256,
                                                  gn_gamma + l * 128, gn_beta + l * 128,
                                                  gn_alpha + l * 128,
                                                  wt + (size_t)(5 + l) * 16384,
                                                  gat_asrc + l * 128, gat_adst + l * 128,
                                                  xw, al, ar, N);
        agg_k<2><<<gW, 256, 0, stream>>>(xw, rp, er, nullptr, al, ar, gat_b + l * 128, g, N);
        moments_k<<<240, 256, 0, stream>>>(g, mom + (2 * l + 1) * 256, n32);
    }

    // final norm + output conv (C -> 1) + leaky
    norm_ydot_k<<<gW, 256, 0, stream>>>(x, g, mom + 9 * 256, gn_gamma + 4 * 128,
                                        gn_beta + 4 * 128, gn_alpha + 4 * 128, Wout, yv, N);
    aggs_k<<<gW, 256, 0, stream>>>(yv, rp, er, dinv, b_out, xs, N);

    // FC head
    fc1_k<<<(N + 255) / 256, 256, 0, stream>>>(xs, fc_W1, hacc, N);
    fc2_k<<<gP, 256, 0, stream>>>(hacc, fc_b1, fc_W2, fc_b2, (float*)d_out, P);
}